// Round 1
// baseline (458.197 us; speedup 1.0000x reference)
//
#include <hip/hip_runtime.h>
#include <hip/hip_bf16.h>

// GCN 2-layer forward. Strategy:
//   deg count -> exclusive scan -> CSR build (pull-based aggregation, no float atomics)
//   hs = dinv[i] * (x @ W1)            (LDS-tiled skinny GEMM, 4x4 reg tile)
//   pull1: hs2[j] = dinv[j] * dot(relu(dinv[j]*(sum_in hs + hs[j]) + b1), W2)
//   pull2: out[j] = dinv[j] * (sum_in hs2 + hs2[j]) + b2

__device__ __forceinline__ bool detect_i64(const unsigned* u) {
    // If edge_index is int64 (values < 2^31), every odd dword is 0.
    unsigned acc = 0;
#pragma unroll
    for (int i = 1; i <= 32; ++i) acc |= u[2 * i + 1];
    return acc == 0u;
}

__device__ __forceinline__ int load_edge(const void* ei, bool is64, long long idx) {
    if (is64) return (int)((const long long*)ei)[idx];
    return ((const int*)ei)[idx];
}

__global__ __launch_bounds__(256) void count_kernel(const void* ei, int* deg_i, int E) {
    bool is64 = detect_i64((const unsigned*)ei);
    int e = blockIdx.x * blockDim.x + threadIdx.x;
    if (e >= E) return;
    int c = load_edge(ei, is64, (long long)E + e);
    atomicAdd(&deg_i[c], 1);
}

__global__ __launch_bounds__(256) void scan1_kernel(const int* __restrict__ deg_i,
                                                    int* __restrict__ bsum, int N) {
    __shared__ int red[256];
    int b = blockIdx.x, t = threadIdx.x;
    int base = b * 1024 + t * 4;
    int s = 0;
#pragma unroll
    for (int i = 0; i < 4; ++i) {
        int idx = base + i;
        if (idx < N) s += deg_i[idx];
    }
    red[t] = s;
    __syncthreads();
#pragma unroll
    for (int off = 128; off >= 1; off >>= 1) {
        if (t < off) red[t] += red[t + off];
        __syncthreads();
    }
    if (t == 0) bsum[b] = red[0];
}

__global__ void scan_mid_kernel(const int* __restrict__ bsum, int* __restrict__ boff,
                                int NBLK) {
    if (threadIdx.x == 0 && blockIdx.x == 0) {
        int run = 0;
        for (int b = 0; b < NBLK; ++b) {
            boff[b] = run;
            run += bsum[b];
        }
    }
}

__global__ __launch_bounds__(256) void scan2_kernel(const int* __restrict__ deg_i,
                                                    const int* __restrict__ boff,
                                                    int* __restrict__ offs,
                                                    int* __restrict__ cursor, int N) {
    __shared__ int tmp[256];
    int b = blockIdx.x, t = threadIdx.x;
    int base = b * 1024 + t * 4;
    int v[4];
    int s = 0;
#pragma unroll
    for (int i = 0; i < 4; ++i) {
        v[i] = (base + i < N) ? deg_i[base + i] : 0;
        s += v[i];
    }
    tmp[t] = s;
    __syncthreads();
    // Hillis-Steele inclusive scan of 256 thread-sums
    for (int off = 1; off < 256; off <<= 1) {
        int xv = (t >= off) ? tmp[t - off] : 0;
        __syncthreads();
        tmp[t] += xv;
        __syncthreads();
    }
    int excl = tmp[t] - s + boff[b];
#pragma unroll
    for (int i = 0; i < 4; ++i) {
        int idx = base + i;
        if (idx < N) {
            offs[idx] = excl;
            cursor[idx] = excl;
            excl += v[i];
        }
    }
}

__global__ __launch_bounds__(256) void scatter_kernel(const void* ei, int* cursor,
                                                      int* __restrict__ csr, int E) {
    bool is64 = detect_i64((const unsigned*)ei);
    int e = blockIdx.x * blockDim.x + threadIdx.x;
    if (e >= E) return;
    int r = load_edge(ei, is64, e);
    int c = load_edge(ei, is64, (long long)E + e);
    int pos = atomicAdd(&cursor[c], 1);
    csr[pos] = r;
}

__device__ __forceinline__ void fma4(float4& a, float s, const float4& w) {
    a.x = fmaf(s, w.x, a.x);
    a.y = fmaf(s, w.y, a.y);
    a.z = fmaf(s, w.z, a.z);
    a.w = fmaf(s, w.w, a.w);
}

// hs[i][j] = rsqrt(deg[i]+1) * sum_k x[i][k] * W1[k][j]
// Block: 64 rows. LDS: x tile [64][132] (pad->2-way bank, free) + W1 [128][64].
// Thread: 4 rows x 4 cols register tile, float4 LDS reads (broadcast-dedup'd).
__global__ __launch_bounds__(256) void gemm1_kernel(const float* __restrict__ x,
                                                    const float* __restrict__ W1,
                                                    const int* __restrict__ deg_i,
                                                    float* __restrict__ hs, int N) {
    __shared__ float xs[64][132];
    __shared__ float Wl[128][64];
    int t = threadIdx.x;
    const float4* W4 = (const float4*)W1;
    float4* Wl4 = (float4*)&Wl[0][0];
#pragma unroll
    for (int i = 0; i < 8; ++i) Wl4[t + 256 * i] = W4[t + 256 * i];
    int row0 = blockIdx.x * 64;
    const float4* x4 = (const float4*)x;
#pragma unroll
    for (int i = 0; i < 8; ++i) {
        int idx = t + 256 * i;  // 0..2047: row = idx>>5, f4col = idx&31
        int r = idx >> 5;
        int gr = row0 + r;
        float4 v = (gr < N) ? x4[(long long)gr * 32 + (idx & 31)]
                            : make_float4(0.f, 0.f, 0.f, 0.f);
        *(float4*)&xs[r][(idx & 31) * 4] = v;
    }
    __syncthreads();
    int rg = t >> 4;   // 0..15 -> rows rg*4..rg*4+3
    int cg = t & 15;   // cols cg*4..cg*4+3
    float4 acc[4];
#pragma unroll
    for (int i = 0; i < 4; ++i) acc[i] = make_float4(0.f, 0.f, 0.f, 0.f);
#pragma unroll 2
    for (int kk = 0; kk < 128; kk += 4) {
        float4 w0 = *(const float4*)&Wl[kk + 0][cg * 4];
        float4 w1 = *(const float4*)&Wl[kk + 1][cg * 4];
        float4 w2 = *(const float4*)&Wl[kk + 2][cg * 4];
        float4 w3 = *(const float4*)&Wl[kk + 3][cg * 4];
#pragma unroll
        for (int i = 0; i < 4; ++i) {
            float4 xv = *(const float4*)&xs[rg * 4 + i][kk];
            fma4(acc[i], xv.x, w0);
            fma4(acc[i], xv.y, w1);
            fma4(acc[i], xv.z, w2);
            fma4(acc[i], xv.w, w3);
        }
    }
#pragma unroll
    for (int i = 0; i < 4; ++i) {
        int gr = row0 + rg * 4 + i;
        if (gr < N) {
            float dinv = rsqrtf((float)deg_i[gr] + 1.0f);
            float4 o;
            o.x = acc[i].x * dinv;
            o.y = acc[i].y * dinv;
            o.z = acc[i].z * dinv;
            o.w = acc[i].w * dinv;
            *(float4*)&hs[(long long)gr * 64 + cg * 4] = o;
        }
    }
}

// One 64-lane wave per node j; lane = feature. Gathers hs rows of its in-edges,
// adds self-loop, applies dinv+bias+relu, dots with W2 (wave reduce), pre-scales
// by dinv for layer 2.
__global__ __launch_bounds__(256) void pull1_kernel(
    const float* __restrict__ hs, const int* __restrict__ offs,
    const int* __restrict__ deg_i, const int* __restrict__ csr,
    const float* __restrict__ b1, const float* __restrict__ W2,
    float* __restrict__ hs2, int N) {
    int gid = blockIdx.x * blockDim.x + threadIdx.x;
    int w = gid >> 6;
    int lane = gid & 63;
    if (w >= N) return;
    float dinv = rsqrtf((float)deg_i[w] + 1.0f);
    float acc = hs[(long long)w * 64 + lane];  // self-loop term
    int s = offs[w];
    int cnt = deg_i[w];
    for (int base = 0; base < cnt; base += 64) {
        int rem = cnt - base;
        int m = rem < 64 ? rem : 64;
        int r = (lane < m) ? csr[s + base + lane] : 0;
        for (int tt = 0; tt < m; ++tt) {
            int rr = __shfl(r, tt);
            acc += hs[(long long)rr * 64 + lane];
        }
    }
    float h1 = fmaxf(fmaf(dinv, acc, b1[lane]), 0.0f);
    float p = h1 * W2[lane];
#pragma unroll
    for (int off = 32; off >= 1; off >>= 1) p += __shfl_xor(p, off);
    if (lane == 0) hs2[w] = dinv * p;
}

__global__ __launch_bounds__(256) void pull2_kernel(
    const float* __restrict__ hs2, const int* __restrict__ offs,
    const int* __restrict__ deg_i, const int* __restrict__ csr,
    const float* __restrict__ b2, float* __restrict__ out, int N) {
    int i = blockIdx.x * blockDim.x + threadIdx.x;
    if (i >= N) return;
    float dinv = rsqrtf((float)deg_i[i] + 1.0f);
    float acc = hs2[i];  // self-loop
    int s = offs[i], cnt = deg_i[i];
    for (int k = 0; k < cnt; ++k) acc += hs2[csr[s + k]];
    out[i] = fmaf(dinv, acc, b2[0]);
}

extern "C" void kernel_launch(void* const* d_in, const int* in_sizes, int n_in,
                              void* d_out, int out_size, void* d_ws, size_t ws_size,
                              hipStream_t stream) {
    const float* x = (const float*)d_in[0];
    const void* ei = d_in[1];
    const float* W1 = (const float*)d_in[2];
    const float* b1 = (const float*)d_in[3];
    const float* W2 = (const float*)d_in[4];
    const float* b2 = (const float*)d_in[5];
    float* out = (float*)d_out;

    int N = in_sizes[0] / 128;
    int E = in_sizes[1] / 2;
    int NBLK = (N + 1023) / 1024;

    char* p = (char*)d_ws;
    float* hs = (float*)p;      p += (size_t)N * 64 * sizeof(float);
    float* hs2 = (float*)p;     p += (size_t)N * sizeof(float);
    int* deg_i = (int*)p;       p += (size_t)N * sizeof(int);
    int* offs = (int*)p;        p += (size_t)N * sizeof(int);
    int* cursor = (int*)p;      p += (size_t)N * sizeof(int);
    int* csr = (int*)p;         p += (size_t)E * sizeof(int);
    int* bsum = (int*)p;        p += (size_t)NBLK * sizeof(int);
    int* boff = (int*)p;        p += (size_t)NBLK * sizeof(int);

    hipMemsetAsync(deg_i, 0, (size_t)N * sizeof(int), stream);
    count_kernel<<<(E + 255) / 256, 256, 0, stream>>>(ei, deg_i, E);
    scan1_kernel<<<NBLK, 256, 0, stream>>>(deg_i, bsum, N);
    scan_mid_kernel<<<1, 64, 0, stream>>>(bsum, boff, NBLK);
    scan2_kernel<<<NBLK, 256, 0, stream>>>(deg_i, boff, offs, cursor, N);
    scatter_kernel<<<(E + 255) / 256, 256, 0, stream>>>(ei, cursor, csr, E);
    gemm1_kernel<<<(N + 63) / 64, 256, 0, stream>>>(x, W1, deg_i, hs, N);
    pull1_kernel<<<((size_t)N * 64 + 255) / 256, 256, 0, stream>>>(hs, offs, deg_i, csr,
                                                                   b1, W2, hs2, N);
    pull2_kernel<<<(N + 255) / 256, 256, 0, stream>>>(hs2, offs, deg_i, csr, b2, out, N);
}

// Round 2
// 265.131 us; speedup vs baseline: 1.7282x; 1.7282x over previous
//
#include <hip/hip_runtime.h>
#include <hip/hip_bf16.h>

// GCN 2-layer forward, R2.
// CSR build via 2-level counting sort (no random 4B scatter, no global count atomics):
//   hist0: 256-bucket histogram (bucket = col>>9)       [LDS atomics, coalesced reads]
//   bscan: exclusive scan of bucket counts -> bases/cursors
//   binA : bucket-bin packed (row<<9|col&511) u32 pairs  [runs of ~128B per (block,bucket)]
//   binB : per-bucket (512 nodes, 32KB CSR window) count+scan+scatter, all L2-resident
// Then:
//   gemm1: hs = dinv * (x @ W1)        (LDS-tiled, 4x4 reg tile)
//   pull1: hs2[j] = dinv_j * dot(relu(dinv_j*(sum_in hs + hs[j]) + b1), W2)
//   pull2: out[j] = dinv_j * (sum_in hs2 + hs2[j]) + b2

#define SHIFT 9
#define BMASK ((1 << SHIFT) - 1)
#define NBUCK 256

__device__ __forceinline__ bool detect_i64(const unsigned* u) {
    // If edge_index is int64 (values < 2^31), every odd dword is 0.
    unsigned acc = 0;
#pragma unroll
    for (int i = 1; i <= 32; ++i) acc |= u[2 * i + 1];
    return acc == 0u;
}

__device__ __forceinline__ int load_edge(const void* ei, bool is64, long long idx) {
    if (is64) return (int)((const long long*)ei)[idx];
    return ((const int*)ei)[idx];
}

__global__ __launch_bounds__(256) void hist0_kernel(const void* ei, int* bhist, int E) {
    bool is64 = detect_i64((const unsigned*)ei);
    __shared__ int h[NBUCK];
    int t = threadIdx.x;
    h[t] = 0;
    __syncthreads();
    for (long long e = (long long)blockIdx.x * blockDim.x + t; e < E;
         e += (long long)gridDim.x * blockDim.x) {
        int c = load_edge(ei, is64, (long long)E + e);
        atomicAdd(&h[c >> SHIFT], 1);
    }
    __syncthreads();
    if (h[t]) atomicAdd(&bhist[t], h[t]);
}

__global__ void bscan_kernel(const int* __restrict__ bhist, int* __restrict__ bbase,
                             int* __restrict__ bcursor, int* __restrict__ offs,
                             int N, int E) {
    __shared__ int tmp[NBUCK];
    int t = threadIdx.x;
    int v = bhist[t];
    tmp[t] = v;
    __syncthreads();
    for (int off = 1; off < NBUCK; off <<= 1) {
        int xv = (t >= off) ? tmp[t - off] : 0;
        __syncthreads();
        tmp[t] += xv;
        __syncthreads();
    }
    int excl = tmp[t] - v;
    bbase[t] = excl;
    bcursor[t] = excl;
    if (t == 0) {
        bbase[NBUCK] = E;
        offs[N] = E;  // CSR sentinel
    }
}

__global__ __launch_bounds__(256) void binA_kernel(const void* ei, int* bcursor,
                                                   unsigned* __restrict__ pairs, int E) {
    bool is64 = detect_i64((const unsigned*)ei);
    __shared__ int hist[NBUCK];
    __shared__ int base[NBUCK];
    int t = threadIdx.x;
    long long per = ((long long)E + gridDim.x - 1) / gridDim.x;
    long long e0 = (long long)blockIdx.x * per;
    long long e1 = e0 + per;
    if (e1 > E) e1 = E;
    hist[t] = 0;
    __syncthreads();
    for (long long e = e0 + t; e < e1; e += 256) {
        int c = load_edge(ei, is64, (long long)E + e);
        atomicAdd(&hist[c >> SHIFT], 1);
    }
    __syncthreads();
    base[t] = hist[t] ? atomicAdd(&bcursor[t], hist[t]) : 0;
    __syncthreads();
    hist[t] = 0;
    __syncthreads();
    for (long long e = e0 + t; e < e1; e += 256) {
        int r = load_edge(ei, is64, e);
        int c = load_edge(ei, is64, (long long)E + e);
        int b = c >> SHIFT;
        int rk = atomicAdd(&hist[b], 1);
        pairs[base[b] + rk] = ((unsigned)r << SHIFT) | (unsigned)(c & BMASK);
    }
}

__global__ __launch_bounds__(256) void binB_kernel(const unsigned* __restrict__ pairs,
                                                   const int* __restrict__ bbase,
                                                   int* __restrict__ csr,
                                                   int* __restrict__ offs, int N) {
    __shared__ int cnt[1 << SHIFT];
    __shared__ int cur[1 << SHIFT];
    __shared__ int tmp[256];
    int b = blockIdx.x, t = threadIdx.x;
    int start = bbase[b], end = bbase[b + 1];
    cnt[t] = 0;
    cnt[t + 256] = 0;
    __syncthreads();
    for (int i = start + t; i < end; i += 256) atomicAdd(&cnt[pairs[i] & BMASK], 1);
    __syncthreads();
    int c0 = cnt[2 * t], c1 = cnt[2 * t + 1];
    int s = c0 + c1;
    tmp[t] = s;
    __syncthreads();
    for (int off = 1; off < 256; off <<= 1) {
        int xv = (t >= off) ? tmp[t - off] : 0;
        __syncthreads();
        tmp[t] += xv;
        __syncthreads();
    }
    int excl = tmp[t] - s;
    int p0 = start + excl;
    int p1 = p0 + c0;
    cur[2 * t] = p0;
    cur[2 * t + 1] = p1;
    int node0 = (b << SHIFT) + 2 * t;
    if (node0 < N) offs[node0] = p0;
    if (node0 + 1 < N) offs[node0 + 1] = p1;
    __syncthreads();
    for (int i = start + t; i < end; i += 256) {
        unsigned p = pairs[i];
        int pos = atomicAdd(&cur[p & BMASK], 1);
        csr[pos] = p >> SHIFT;
    }
}

__device__ __forceinline__ void fma4(float4& a, float s, const float4& w) {
    a.x = fmaf(s, w.x, a.x);
    a.y = fmaf(s, w.y, a.y);
    a.z = fmaf(s, w.z, a.z);
    a.w = fmaf(s, w.w, a.w);
}

// hs[i][j] = rsqrt(deg[i]+1) * sum_k x[i][k] * W1[k][j]
__global__ __launch_bounds__(256) void gemm1_kernel(const float* __restrict__ x,
                                                    const float* __restrict__ W1,
                                                    const int* __restrict__ offs,
                                                    float* __restrict__ hs, int N) {
    __shared__ float xs[64][132];
    __shared__ float Wl[128][64];
    int t = threadIdx.x;
    const float4* W4 = (const float4*)W1;
    float4* Wl4 = (float4*)&Wl[0][0];
#pragma unroll
    for (int i = 0; i < 8; ++i) Wl4[t + 256 * i] = W4[t + 256 * i];
    int row0 = blockIdx.x * 64;
    const float4* x4 = (const float4*)x;
#pragma unroll
    for (int i = 0; i < 8; ++i) {
        int idx = t + 256 * i;
        int r = idx >> 5;
        int gr = row0 + r;
        float4 v = (gr < N) ? x4[(long long)gr * 32 + (idx & 31)]
                            : make_float4(0.f, 0.f, 0.f, 0.f);
        *(float4*)&xs[r][(idx & 31) * 4] = v;
    }
    __syncthreads();
    int rg = t >> 4;
    int cg = t & 15;
    float4 acc[4];
#pragma unroll
    for (int i = 0; i < 4; ++i) acc[i] = make_float4(0.f, 0.f, 0.f, 0.f);
#pragma unroll 2
    for (int kk = 0; kk < 128; kk += 4) {
        float4 w0 = *(const float4*)&Wl[kk + 0][cg * 4];
        float4 w1 = *(const float4*)&Wl[kk + 1][cg * 4];
        float4 w2 = *(const float4*)&Wl[kk + 2][cg * 4];
        float4 w3 = *(const float4*)&Wl[kk + 3][cg * 4];
#pragma unroll
        for (int i = 0; i < 4; ++i) {
            float4 xv = *(const float4*)&xs[rg * 4 + i][kk];
            fma4(acc[i], xv.x, w0);
            fma4(acc[i], xv.y, w1);
            fma4(acc[i], xv.z, w2);
            fma4(acc[i], xv.w, w3);
        }
    }
#pragma unroll
    for (int i = 0; i < 4; ++i) {
        int gr = row0 + rg * 4 + i;
        if (gr < N) {
            float dinv = rsqrtf((float)(offs[gr + 1] - offs[gr]) + 1.0f);
            float4 o;
            o.x = acc[i].x * dinv;
            o.y = acc[i].y * dinv;
            o.z = acc[i].z * dinv;
            o.w = acc[i].w * dinv;
            *(float4*)&hs[(long long)gr * 64 + cg * 4] = o;
        }
    }
}

// One wave per node; lane = feature. 4 independent accumulators for MLP.
__global__ __launch_bounds__(256) void pull1_kernel(
    const float* __restrict__ hs, const int* __restrict__ offs,
    const int* __restrict__ csr, const float* __restrict__ b1,
    const float* __restrict__ W2, float* __restrict__ hs2, int N) {
    int gid = blockIdx.x * blockDim.x + threadIdx.x;
    int w = gid >> 6;
    int lane = gid & 63;
    if (w >= N) return;
    int s = offs[w];
    int cnt = offs[w + 1] - s;
    float dinv = rsqrtf((float)cnt + 1.0f);
    float a0 = hs[(long long)w * 64 + lane];  // self-loop term
    float a1 = 0.f, a2 = 0.f, a3 = 0.f;
    for (int base = 0; base < cnt; base += 64) {
        int rem = cnt - base;
        int m = rem < 64 ? rem : 64;
        int r = (lane < m) ? csr[s + base + lane] : 0;
        int tt = 0;
        for (; tt + 4 <= m; tt += 4) {
            int r0 = __shfl(r, tt);
            int r1 = __shfl(r, tt + 1);
            int r2 = __shfl(r, tt + 2);
            int r3 = __shfl(r, tt + 3);
            a0 += hs[(long long)r0 * 64 + lane];
            a1 += hs[(long long)r1 * 64 + lane];
            a2 += hs[(long long)r2 * 64 + lane];
            a3 += hs[(long long)r3 * 64 + lane];
        }
        for (; tt < m; ++tt) a0 += hs[(long long)__shfl(r, tt) * 64 + lane];
    }
    float acc = (a0 + a1) + (a2 + a3);
    float h1 = fmaxf(fmaf(dinv, acc, b1[lane]), 0.0f);
    float p = h1 * W2[lane];
#pragma unroll
    for (int off = 32; off >= 1; off >>= 1) p += __shfl_xor(p, off);
    if (lane == 0) hs2[w] = dinv * p;
}

__global__ __launch_bounds__(256) void pull2_kernel(
    const float* __restrict__ hs2, const int* __restrict__ offs,
    const int* __restrict__ csr, const float* __restrict__ b2,
    float* __restrict__ out, int N) {
    int i = blockIdx.x * blockDim.x + threadIdx.x;
    if (i >= N) return;
    int s = offs[i];
    int cnt = offs[i + 1] - s;
    float dinv = rsqrtf((float)cnt + 1.0f);
    float a0 = hs2[i];  // self-loop
    float a1 = 0.f, a2 = 0.f, a3 = 0.f;
    int k = 0;
    for (; k + 4 <= cnt; k += 4) {
        a0 += hs2[csr[s + k]];
        a1 += hs2[csr[s + k + 1]];
        a2 += hs2[csr[s + k + 2]];
        a3 += hs2[csr[s + k + 3]];
    }
    for (; k < cnt; ++k) a0 += hs2[csr[s + k]];
    out[i] = fmaf(dinv, (a0 + a1) + (a2 + a3), b2[0]);
}

extern "C" void kernel_launch(void* const* d_in, const int* in_sizes, int n_in,
                              void* d_out, int out_size, void* d_ws, size_t ws_size,
                              hipStream_t stream) {
    const float* x = (const float*)d_in[0];
    const void* ei = d_in[1];
    const float* W1 = (const float*)d_in[2];
    const float* b1 = (const float*)d_in[3];
    const float* W2 = (const float*)d_in[4];
    const float* b2 = (const float*)d_in[5];
    float* out = (float*)d_out;

    int N = in_sizes[0] / 128;
    int E = in_sizes[1] / 2;
    int NB = (N + (1 << SHIFT) - 1) >> SHIFT;  // buckets actually used (<= 256)

    char* p = (char*)d_ws;
    float* hs = (float*)p;       p += (size_t)N * 64 * sizeof(float);
    float* hs2 = (float*)p;      p += (size_t)N * sizeof(float);
    int* offs = (int*)p;         p += (size_t)(N + 1) * sizeof(int);
    unsigned* pairs = (unsigned*)p; p += (size_t)E * sizeof(unsigned);
    int* csr = (int*)p;          p += (size_t)E * sizeof(int);
    int* bhist = (int*)p;        p += NBUCK * sizeof(int);
    int* bbase = (int*)p;        p += (NBUCK + 1) * sizeof(int);
    int* bcursor = (int*)p;      p += NBUCK * sizeof(int);

    hipMemsetAsync(bhist, 0, NBUCK * sizeof(int), stream);
    hist0_kernel<<<256, 256, 0, stream>>>(ei, bhist, E);
    bscan_kernel<<<1, NBUCK, 0, stream>>>(bhist, bbase, bcursor, offs, N, E);
    binA_kernel<<<256, 256, 0, stream>>>(ei, bcursor, pairs, E);
    binB_kernel<<<NB, 256, 0, stream>>>(pairs, bbase, csr, offs, N);
    gemm1_kernel<<<(N + 63) / 64, 256, 0, stream>>>(x, W1, offs, hs, N);
    pull1_kernel<<<((size_t)N * 64 + 255) / 256, 256, 0, stream>>>(hs, offs, csr, b1,
                                                                   W2, hs2, N);
    pull2_kernel<<<(N + 255) / 256, 256, 0, stream>>>(hs2, offs, csr, b2, out, N);
}

// Round 3
// 230.574 us; speedup vs baseline: 1.9872x; 1.1499x over previous
//
#include <hip/hip_runtime.h>
#include <hip/hip_bf16.h>

// GCN 2-layer forward, R3.
//   initcur: per-bucket padded-region cursors (no hist0/bscan passes)
//   binA   : bucket-bin packed (row<<9|col&511) u32, per-wave LDS hist -> block runs
//   binB   : per-bucket count+scan+scatter -> padded CSR + offs/deg arrays
//   gemm1  : hs_bf16 = dinv * (x @ W1)   (LDS-tiled, 4x4 reg tile, bf16-packed out)
//   pull1  : 2 edges/wave-instr bf16 gather; hs2[j] = dinv*dot(relu(dinv*agg+b1),W2)
//   pull2  : out[j] = dinv*(sum hs2) + b2   (hs2 table L2-resident)

#define SHIFT 9
#define BMASK ((1 << SHIFT) - 1)

__device__ __forceinline__ bool detect_i64(const unsigned* u) {
    unsigned acc = 0;
#pragma unroll
    for (int i = 1; i <= 32; ++i) acc |= u[2 * i + 1];
    return acc == 0u;
}

__device__ __forceinline__ int load_edge(const void* ei, bool is64, long long idx) {
    if (is64) return ((const int*)ei)[idx << 1];  // low dword of little-endian i64
    return ((const int*)ei)[idx];
}

__device__ __forceinline__ unsigned bf16_rn(float x) {
    unsigned u = __float_as_uint(x);
    return (u + 0x7fffu + ((u >> 16) & 1u)) >> 16;
}
__device__ __forceinline__ unsigned pack_bf2(float a, float b) {
    return bf16_rn(a) | (bf16_rn(b) << 16);
}
__device__ __forceinline__ float bflo(unsigned v) { return __uint_as_float(v << 16); }
__device__ __forceinline__ float bfhi(unsigned v) {
    return __uint_as_float(v & 0xffff0000u);
}

__global__ void initcur_kernel(int* gcursor, int cap) {
    gcursor[threadIdx.x] = threadIdx.x * cap;
}

__global__ __launch_bounds__(256) void binA_kernel(const void* ei, int* gcursor,
                                                   unsigned* __restrict__ pairs, int E) {
    bool is64 = detect_i64((const unsigned*)ei);
    __shared__ int whist[4][256];
    __shared__ int bcur[256];
    int t = threadIdx.x;
    int wid = t >> 6;
    long long per = ((long long)E + gridDim.x - 1) / gridDim.x;
    long long e0 = (long long)blockIdx.x * per;
    long long e1 = e0 + per;
    if (e1 > E) e1 = E;
    whist[0][t] = 0; whist[1][t] = 0; whist[2][t] = 0; whist[3][t] = 0;
    __syncthreads();
    for (long long e = e0 + t; e < e1; e += 256) {
        int c = load_edge(ei, is64, (long long)E + e);
        atomicAdd(&whist[wid][c >> SHIFT], 1);  // intra-wave conflicts only (~1.3-way)
    }
    __syncthreads();
    int tot = whist[0][t] + whist[1][t] + whist[2][t] + whist[3][t];
    bcur[t] = tot ? atomicAdd(&gcursor[t], tot) : 0;
    __syncthreads();
    for (long long e = e0 + t; e < e1; e += 256) {
        int r = load_edge(ei, is64, e);
        int c = load_edge(ei, is64, (long long)E + e);
        int b = c >> SHIFT;
        int rk = atomicAdd(&bcur[b], 1);
        pairs[rk] = ((unsigned)r << SHIFT) | (unsigned)(c & BMASK);
    }
}

__global__ __launch_bounds__(256) void binB_kernel(const unsigned* __restrict__ pairs,
                                                   const int* __restrict__ gcursor,
                                                   int* __restrict__ csr,
                                                   int* __restrict__ offs,
                                                   int* __restrict__ deg, int N,
                                                   int cap) {
    __shared__ int cnt[1 << SHIFT];
    __shared__ int cur[1 << SHIFT];
    __shared__ int tmp[256];
    int b = blockIdx.x, t = threadIdx.x;
    int start = b * cap, end = gcursor[b];
    cnt[t] = 0;
    cnt[t + 256] = 0;
    __syncthreads();
    for (int i = start + t; i < end; i += 256) atomicAdd(&cnt[pairs[i] & BMASK], 1);
    __syncthreads();
    int c0 = cnt[2 * t], c1 = cnt[2 * t + 1];
    int s = c0 + c1;
    tmp[t] = s;
    __syncthreads();
    for (int off = 1; off < 256; off <<= 1) {
        int xv = (t >= off) ? tmp[t - off] : 0;
        __syncthreads();
        tmp[t] += xv;
        __syncthreads();
    }
    int excl = tmp[t] - s;
    int p0 = start + excl;
    int p1 = p0 + c0;
    cur[2 * t] = p0;
    cur[2 * t + 1] = p1;
    int node0 = (b << SHIFT) + 2 * t;
    if (node0 < N) { offs[node0] = p0; deg[node0] = c0; }
    if (node0 + 1 < N) { offs[node0 + 1] = p1; deg[node0 + 1] = c1; }
    __syncthreads();
    for (int i = start + t; i < end; i += 256) {
        unsigned p = pairs[i];
        int pos = atomicAdd(&cur[p & BMASK], 1);
        csr[pos] = (int)(p >> SHIFT);
    }
}

__device__ __forceinline__ void fma4(float4& a, float s, const float4& w) {
    a.x = fmaf(s, w.x, a.x);
    a.y = fmaf(s, w.y, a.y);
    a.z = fmaf(s, w.z, a.z);
    a.w = fmaf(s, w.w, a.w);
}

// hs_u[i][k] packs feats (2k, 2k+1) of dinv_i * (x_i @ W1) as 2xbf16.
__global__ __launch_bounds__(256) void gemm1_kernel(const float* __restrict__ x,
                                                    const float* __restrict__ W1,
                                                    const int* __restrict__ deg,
                                                    unsigned* __restrict__ hs_u, int N) {
    __shared__ float xs[64][132];
    __shared__ float Wl[128][64];
    int t = threadIdx.x;
    const float4* W4 = (const float4*)W1;
    float4* Wl4 = (float4*)&Wl[0][0];
#pragma unroll
    for (int i = 0; i < 8; ++i) Wl4[t + 256 * i] = W4[t + 256 * i];
    int row0 = blockIdx.x * 64;
    const float4* x4 = (const float4*)x;
#pragma unroll
    for (int i = 0; i < 8; ++i) {
        int idx = t + 256 * i;
        int r = idx >> 5;
        int gr = row0 + r;
        float4 v = (gr < N) ? x4[(long long)gr * 32 + (idx & 31)]
                            : make_float4(0.f, 0.f, 0.f, 0.f);
        *(float4*)&xs[r][(idx & 31) * 4] = v;
    }
    __syncthreads();
    int rg = t >> 4;
    int cg = t & 15;
    float4 acc[4];
#pragma unroll
    for (int i = 0; i < 4; ++i) acc[i] = make_float4(0.f, 0.f, 0.f, 0.f);
#pragma unroll 2
    for (int kk = 0; kk < 128; kk += 4) {
        float4 w0 = *(const float4*)&Wl[kk + 0][cg * 4];
        float4 w1 = *(const float4*)&Wl[kk + 1][cg * 4];
        float4 w2 = *(const float4*)&Wl[kk + 2][cg * 4];
        float4 w3 = *(const float4*)&Wl[kk + 3][cg * 4];
#pragma unroll
        for (int i = 0; i < 4; ++i) {
            float4 xv = *(const float4*)&xs[rg * 4 + i][kk];
            fma4(acc[i], xv.x, w0);
            fma4(acc[i], xv.y, w1);
            fma4(acc[i], xv.z, w2);
            fma4(acc[i], xv.w, w3);
        }
    }
#pragma unroll
    for (int i = 0; i < 4; ++i) {
        int gr = row0 + rg * 4 + i;
        if (gr < N) {
            float dinv = rsqrtf((float)deg[gr] + 1.0f);
            unsigned u0 = pack_bf2(acc[i].x * dinv, acc[i].y * dinv);
            unsigned u1 = pack_bf2(acc[i].z * dinv, acc[i].w * dinv);
            *(uint2*)&hs_u[(size_t)gr * 32 + cg * 2] = make_uint2(u0, u1);
        }
    }
}

// One wave per node. Lanes 0-31 gather even-indexed edges, 32-63 odd-indexed;
// lane k holds feats (2k, 2k+1). Merge halves via shfl_xor(32) at the end.
__global__ __launch_bounds__(256) void pull1_kernel(
    const unsigned* __restrict__ hs_u, const int* __restrict__ offs,
    const int* __restrict__ deg, const int* __restrict__ csr,
    const float* __restrict__ b1, const float* __restrict__ W2,
    float* __restrict__ hs2, int N) {
    int gid = blockIdx.x * blockDim.x + threadIdx.x;
    int w = gid >> 6;
    if (w >= N) return;
    int lane = gid & 63;
    int half = lane >> 5;
    int k = lane & 31;
    int s = offs[w];
    int cnt = deg[w];
    float dinv = rsqrtf((float)cnt + 1.0f);
    unsigned sv = hs_u[(size_t)w * 32 + k];  // self-loop, counted once (half 0)
    float ae0 = half ? 0.f : bflo(sv);
    float ao0 = half ? 0.f : bfhi(sv);
    float ae1 = 0.f, ao1 = 0.f;
    for (int base = 0; base < cnt; base += 64) {
        int rem = cnt - base;
        int m = rem < 64 ? rem : 64;
        int r = (lane < m) ? csr[s + base + lane] : 0;
        int tt = 0;
        for (; tt + 8 <= m; tt += 8) {
            int r0 = __shfl(r, tt + half);
            int r1 = __shfl(r, tt + 2 + half);
            int r2 = __shfl(r, tt + 4 + half);
            int r3 = __shfl(r, tt + 6 + half);
            unsigned v0 = hs_u[(size_t)r0 * 32 + k];
            unsigned v1 = hs_u[(size_t)r1 * 32 + k];
            unsigned v2 = hs_u[(size_t)r2 * 32 + k];
            unsigned v3 = hs_u[(size_t)r3 * 32 + k];
            ae0 += bflo(v0); ao0 += bfhi(v0);
            ae1 += bflo(v1); ao1 += bfhi(v1);
            ae0 += bflo(v2); ao0 += bfhi(v2);
            ae1 += bflo(v3); ao1 += bfhi(v3);
        }
        for (; tt < m; tt += 2) {
            int idx = tt + half;
            int rr = __shfl(r, idx < m ? idx : m - 1);
            if (idx < m) {
                unsigned v = hs_u[(size_t)rr * 32 + k];
                ae0 += bflo(v);
                ao0 += bfhi(v);
            }
        }
    }
    float ae = ae0 + ae1;
    float ao = ao0 + ao1;
    ae += __shfl_xor(ae, 32);
    ao += __shfl_xor(ao, 32);
    float2 bb = ((const float2*)b1)[k];
    float2 ww = ((const float2*)W2)[k];
    float h1e = fmaxf(fmaf(dinv, ae, bb.x), 0.0f);
    float h1o = fmaxf(fmaf(dinv, ao, bb.y), 0.0f);
    float p = h1e * ww.x + h1o * ww.y;
#pragma unroll
    for (int off = 16; off >= 1; off >>= 1) p += __shfl_xor(p, off);
    if (lane == 0) hs2[w] = dinv * p;
}

__global__ __launch_bounds__(256) void pull2_kernel(
    const float* __restrict__ hs2, const int* __restrict__ offs,
    const int* __restrict__ deg, const int* __restrict__ csr,
    const float* __restrict__ b2, float* __restrict__ out, int N) {
    int i = blockIdx.x * blockDim.x + threadIdx.x;
    if (i >= N) return;
    int s = offs[i];
    int cnt = deg[i];
    float dinv = rsqrtf((float)cnt + 1.0f);
    float a0 = hs2[i];  // self-loop
    float a1 = 0.f, a2 = 0.f, a3 = 0.f;
    int kk = 0;
    for (; kk + 4 <= cnt; kk += 4) {
        a0 += hs2[csr[s + kk]];
        a1 += hs2[csr[s + kk + 1]];
        a2 += hs2[csr[s + kk + 2]];
        a3 += hs2[csr[s + kk + 3]];
    }
    for (; kk < cnt; ++kk) a0 += hs2[csr[s + kk]];
    out[i] = fmaf(dinv, (a0 + a1) + (a2 + a3), b2[0]);
}

extern "C" void kernel_launch(void* const* d_in, const int* in_sizes, int n_in,
                              void* d_out, int out_size, void* d_ws, size_t ws_size,
                              hipStream_t stream) {
    const float* x = (const float*)d_in[0];
    const void* ei = d_in[1];
    const float* W1 = (const float*)d_in[2];
    const float* b1 = (const float*)d_in[3];
    const float* W2 = (const float*)d_in[4];
    const float* b2 = (const float*)d_in[5];
    float* out = (float*)d_out;

    int N = in_sizes[0] / 128;
    int E = in_sizes[1] / 2;
    int NB = (N + (1 << SHIFT) - 1) >> SHIFT;        // buckets used (<= 256)
    int cap = ((2 * (E / NB)) / 256 + 2) * 256;      // 2x mean: safe for random input

    char* p = (char*)d_ws;
    unsigned* hs_u = (unsigned*)p;  p += (size_t)N * 32 * sizeof(unsigned);
    float* hs2 = (float*)p;         p += (size_t)N * sizeof(float);
    int* offs = (int*)p;            p += (size_t)N * sizeof(int);
    int* deg = (int*)p;             p += (size_t)N * sizeof(int);
    unsigned* pairs = (unsigned*)p; p += (size_t)NB * cap * sizeof(unsigned);
    int* csr = (int*)p;             p += (size_t)NB * cap * sizeof(int);
    int* gcursor = (int*)p;         p += 256 * sizeof(int);

    initcur_kernel<<<1, 256, 0, stream>>>(gcursor, cap);
    binA_kernel<<<512, 256, 0, stream>>>(ei, gcursor, pairs, E);
    binB_kernel<<<NB, 256, 0, stream>>>(pairs, gcursor, csr, offs, deg, N, cap);
    gemm1_kernel<<<(N + 63) / 64, 256, 0, stream>>>(x, W1, deg, hs_u, N);
    pull1_kernel<<<((size_t)N * 64 + 255) / 256, 256, 0, stream>>>(hs_u, offs, deg, csr,
                                                                   b1, W2, hs2, N);
    pull2_kernel<<<(N + 255) / 256, 256, 0, stream>>>(hs2, offs, deg, csr, b2, out, N);
}

// Round 4
// 226.083 us; speedup vs baseline: 2.0267x; 1.0199x over previous
//
#include <hip/hip_runtime.h>
#include <hip/hip_bf16.h>

// GCN 2-layer forward, R4.
//   binA   : bucket-bin packed (row<<9|col&511) u32, relative global cursors (memset-init)
//   binB   : per-bucket count+scan+scatter -> padded CSR + offs/deg arrays
//   gemm1  : hs_bf16 = dinv * (x @ W1)   (LDS-tiled, 4x4 reg tile, bf16-packed out)
//   pull1  : OCTET gather - 8 lanes/edge, uint4 (16B) per lane = 8 edges per wave-load.
//            hs2[j] = dinv*dot(relu(dinv*agg+b1),W2)
//   pull2  : out[j] = dinv*(sum hs2) + b2   (hs2 table L2-resident)

#define SHIFT 9
#define BMASK ((1 << SHIFT) - 1)

__device__ __forceinline__ bool detect_i64(const unsigned* u) {
    unsigned acc = 0;
#pragma unroll
    for (int i = 1; i <= 32; ++i) acc |= u[2 * i + 1];
    return acc == 0u;
}

__device__ __forceinline__ int load_edge(const void* ei, bool is64, long long idx) {
    if (is64) return ((const int*)ei)[idx << 1];  // low dword of little-endian i64
    return ((const int*)ei)[idx];
}

__device__ __forceinline__ unsigned bf16_rn(float x) {
    unsigned u = __float_as_uint(x);
    return (u + 0x7fffu + ((u >> 16) & 1u)) >> 16;
}
__device__ __forceinline__ unsigned pack_bf2(float a, float b) {
    return bf16_rn(a) | (bf16_rn(b) << 16);
}
__device__ __forceinline__ float bflo(unsigned v) { return __uint_as_float(v << 16); }
__device__ __forceinline__ float bfhi(unsigned v) {
    return __uint_as_float(v & 0xffff0000u);
}

__global__ __launch_bounds__(256) void binA_kernel(const void* ei, int* gcursor,
                                                   unsigned* __restrict__ pairs, int E,
                                                   int cap) {
    bool is64 = detect_i64((const unsigned*)ei);
    __shared__ int whist[4][256];
    __shared__ int bcur[256];
    int t = threadIdx.x;
    int wid = t >> 6;
    long long per = ((long long)E + gridDim.x - 1) / gridDim.x;
    long long e0 = (long long)blockIdx.x * per;
    long long e1 = e0 + per;
    if (e1 > E) e1 = E;
    whist[0][t] = 0; whist[1][t] = 0; whist[2][t] = 0; whist[3][t] = 0;
    __syncthreads();
    for (long long e = e0 + t; e < e1; e += 256) {
        int c = load_edge(ei, is64, (long long)E + e);
        atomicAdd(&whist[wid][c >> SHIFT], 1);  // intra-wave conflicts only
    }
    __syncthreads();
    int tot = whist[0][t] + whist[1][t] + whist[2][t] + whist[3][t];
    int rel = tot ? atomicAdd(&gcursor[t], tot) : 0;  // relative cursor (memset-0 init)
    bcur[t] = t * cap + rel;
    __syncthreads();
    for (long long e = e0 + t; e < e1; e += 256) {
        int r = load_edge(ei, is64, e);
        int c = load_edge(ei, is64, (long long)E + e);
        int b = c >> SHIFT;
        int rk = atomicAdd(&bcur[b], 1);
        pairs[rk] = ((unsigned)r << SHIFT) | (unsigned)(c & BMASK);
    }
}

__global__ __launch_bounds__(256) void binB_kernel(const unsigned* __restrict__ pairs,
                                                   const int* __restrict__ gcursor,
                                                   int* __restrict__ csr,
                                                   int* __restrict__ offs,
                                                   int* __restrict__ deg, int N,
                                                   int cap) {
    __shared__ int cnt[1 << SHIFT];
    __shared__ int cur[1 << SHIFT];
    __shared__ int tmp[256];
    int b = blockIdx.x, t = threadIdx.x;
    int start = b * cap, end = b * cap + gcursor[b];
    cnt[t] = 0;
    cnt[t + 256] = 0;
    __syncthreads();
    for (int i = start + t; i < end; i += 256) atomicAdd(&cnt[pairs[i] & BMASK], 1);
    __syncthreads();
    int c0 = cnt[2 * t], c1 = cnt[2 * t + 1];
    int s = c0 + c1;
    tmp[t] = s;
    __syncthreads();
    for (int off = 1; off < 256; off <<= 1) {
        int xv = (t >= off) ? tmp[t - off] : 0;
        __syncthreads();
        tmp[t] += xv;
        __syncthreads();
    }
    int excl = tmp[t] - s;
    int p0 = start + excl;
    int p1 = p0 + c0;
    cur[2 * t] = p0;
    cur[2 * t + 1] = p1;
    int node0 = (b << SHIFT) + 2 * t;
    if (node0 < N) { offs[node0] = p0; deg[node0] = c0; }
    if (node0 + 1 < N) { offs[node0 + 1] = p1; deg[node0 + 1] = c1; }
    __syncthreads();
    for (int i = start + t; i < end; i += 256) {
        unsigned p = pairs[i];
        int pos = atomicAdd(&cur[p & BMASK], 1);
        csr[pos] = (int)(p >> SHIFT);
    }
}

__device__ __forceinline__ void fma4(float4& a, float s, const float4& w) {
    a.x = fmaf(s, w.x, a.x);
    a.y = fmaf(s, w.y, a.y);
    a.z = fmaf(s, w.z, a.z);
    a.w = fmaf(s, w.w, a.w);
}

// hs_u[i][k] packs feats (2k, 2k+1) of dinv_i * (x_i @ W1) as 2xbf16.
__global__ __launch_bounds__(256) void gemm1_kernel(const float* __restrict__ x,
                                                    const float* __restrict__ W1,
                                                    const int* __restrict__ deg,
                                                    unsigned* __restrict__ hs_u, int N) {
    __shared__ float xs[64][132];
    __shared__ float Wl[128][64];
    int t = threadIdx.x;
    const float4* W4 = (const float4*)W1;
    float4* Wl4 = (float4*)&Wl[0][0];
#pragma unroll
    for (int i = 0; i < 8; ++i) Wl4[t + 256 * i] = W4[t + 256 * i];
    int row0 = blockIdx.x * 64;
    const float4* x4 = (const float4*)x;
#pragma unroll
    for (int i = 0; i < 8; ++i) {
        int idx = t + 256 * i;
        int r = idx >> 5;
        int gr = row0 + r;
        float4 v = (gr < N) ? x4[(long long)gr * 32 + (idx & 31)]
                            : make_float4(0.f, 0.f, 0.f, 0.f);
        *(float4*)&xs[r][(idx & 31) * 4] = v;
    }
    __syncthreads();
    int rg = t >> 4;
    int cg = t & 15;
    float4 acc[4];
#pragma unroll
    for (int i = 0; i < 4; ++i) acc[i] = make_float4(0.f, 0.f, 0.f, 0.f);
#pragma unroll 2
    for (int kk = 0; kk < 128; kk += 4) {
        float4 w0 = *(const float4*)&Wl[kk + 0][cg * 4];
        float4 w1 = *(const float4*)&Wl[kk + 1][cg * 4];
        float4 w2 = *(const float4*)&Wl[kk + 2][cg * 4];
        float4 w3 = *(const float4*)&Wl[kk + 3][cg * 4];
#pragma unroll
        for (int i = 0; i < 4; ++i) {
            float4 xv = *(const float4*)&xs[rg * 4 + i][kk];
            fma4(acc[i], xv.x, w0);
            fma4(acc[i], xv.y, w1);
            fma4(acc[i], xv.z, w2);
            fma4(acc[i], xv.w, w3);
        }
    }
#pragma unroll
    for (int i = 0; i < 4; ++i) {
        int gr = row0 + rg * 4 + i;
        if (gr < N) {
            float dinv = rsqrtf((float)deg[gr] + 1.0f);
            unsigned u0 = pack_bf2(acc[i].x * dinv, acc[i].y * dinv);
            unsigned u1 = pack_bf2(acc[i].z * dinv, acc[i].w * dinv);
            *(uint2*)&hs_u[(size_t)gr * 32 + cg * 2] = make_uint2(u0, u1);
        }
    }
}

#define ACC8(v)                                    \
    a0 += bflo((v).x); a1 += bfhi((v).x);          \
    a2 += bflo((v).y); a3 += bfhi((v).y);          \
    a4 += bflo((v).z); a5 += bfhi((v).z);          \
    a6 += bflo((v).w); a7 += bfhi((v).w);

#define RED8(off)                                  \
    a0 += __shfl_xor(a0, off); a1 += __shfl_xor(a1, off); \
    a2 += __shfl_xor(a2, off); a3 += __shfl_xor(a3, off); \
    a4 += __shfl_xor(a4, off); a5 += __shfl_xor(a5, off); \
    a6 += __shfl_xor(a6, off); a7 += __shfl_xor(a7, off);

// One wave per node. Octet oid (8 lanes) owns edge tt+oid; lane k of the octet
// loads uint4 = feats 8k..8k+7. One wave-load = 8 edges x 128B.
__global__ __launch_bounds__(256) void pull1_kernel(
    const uint4* __restrict__ hs4, const int* __restrict__ offs,
    const int* __restrict__ deg, const int* __restrict__ csr,
    const float* __restrict__ b1, const float* __restrict__ W2,
    float* __restrict__ hs2, int N) {
    int gid = blockIdx.x * blockDim.x + threadIdx.x;
    int w = gid >> 6;
    if (w >= N) return;
    int lane = gid & 63;
    int oid = lane >> 3;
    int k = lane & 7;
    int s = offs[w];
    int cnt = deg[w];
    float dinv = rsqrtf((float)cnt + 1.0f);
    float a0 = 0.f, a1 = 0.f, a2 = 0.f, a3 = 0.f;
    float a4 = 0.f, a5 = 0.f, a6 = 0.f, a7 = 0.f;
    if (oid == 0) {  // self-loop term, counted once
        uint4 v = hs4[(size_t)w * 8 + k];
        ACC8(v);
    }
    for (int base = 0; base < cnt; base += 64) {
        int rem = cnt - base;
        int m = rem < 64 ? rem : 64;
        int r = (lane < m) ? csr[s + base + lane] : 0;
        int tt = 0;
        for (; tt + 32 <= m; tt += 32) {
            int r0 = __shfl(r, tt + oid);
            int r1 = __shfl(r, tt + 8 + oid);
            int r2 = __shfl(r, tt + 16 + oid);
            int r3 = __shfl(r, tt + 24 + oid);
            uint4 v0 = hs4[(size_t)r0 * 8 + k];
            uint4 v1 = hs4[(size_t)r1 * 8 + k];
            uint4 v2 = hs4[(size_t)r2 * 8 + k];
            uint4 v3 = hs4[(size_t)r3 * 8 + k];
            ACC8(v0); ACC8(v1); ACC8(v2); ACC8(v3);
        }
        for (; tt + 8 <= m; tt += 8) {
            int rr = __shfl(r, tt + oid);
            uint4 v = hs4[(size_t)rr * 8 + k];
            ACC8(v);
        }
        if (tt < m) {
            int idx = tt + oid;
            int rr = __shfl(r, idx < m ? idx : 0);
            if (idx < m) {
                uint4 v = hs4[(size_t)rr * 8 + k];
                ACC8(v);
            }
        }
    }
    RED8(8); RED8(16); RED8(32);  // reduce across octets -> full feature sums
    float4 bA = ((const float4*)b1)[2 * k];
    float4 bB = ((const float4*)b1)[2 * k + 1];
    float4 wA = ((const float4*)W2)[2 * k];
    float4 wB = ((const float4*)W2)[2 * k + 1];
    float p = fmaxf(fmaf(dinv, a0, bA.x), 0.f) * wA.x
            + fmaxf(fmaf(dinv, a1, bA.y), 0.f) * wA.y
            + fmaxf(fmaf(dinv, a2, bA.z), 0.f) * wA.z
            + fmaxf(fmaf(dinv, a3, bA.w), 0.f) * wA.w
            + fmaxf(fmaf(dinv, a4, bB.x), 0.f) * wB.x
            + fmaxf(fmaf(dinv, a5, bB.y), 0.f) * wB.y
            + fmaxf(fmaf(dinv, a6, bB.z), 0.f) * wB.z
            + fmaxf(fmaf(dinv, a7, bB.w), 0.f) * wB.w;
    p += __shfl_xor(p, 1);
    p += __shfl_xor(p, 2);
    p += __shfl_xor(p, 4);
    if (lane == 0) hs2[w] = dinv * p;
}

__global__ __launch_bounds__(256) void pull2_kernel(
    const float* __restrict__ hs2, const int* __restrict__ offs,
    const int* __restrict__ deg, const int* __restrict__ csr,
    const float* __restrict__ b2, float* __restrict__ out, int N) {
    int i = blockIdx.x * blockDim.x + threadIdx.x;
    if (i >= N) return;
    int s = offs[i];
    int cnt = deg[i];
    float dinv = rsqrtf((float)cnt + 1.0f);
    float a0 = hs2[i];  // self-loop
    float a1 = 0.f, a2 = 0.f, a3 = 0.f;
    int kk = 0;
    for (; kk + 4 <= cnt; kk += 4) {
        a0 += hs2[csr[s + kk]];
        a1 += hs2[csr[s + kk + 1]];
        a2 += hs2[csr[s + kk + 2]];
        a3 += hs2[csr[s + kk + 3]];
    }
    for (; kk < cnt; ++kk) a0 += hs2[csr[s + kk]];
    out[i] = fmaf(dinv, (a0 + a1) + (a2 + a3), b2[0]);
}

extern "C" void kernel_launch(void* const* d_in, const int* in_sizes, int n_in,
                              void* d_out, int out_size, void* d_ws, size_t ws_size,
                              hipStream_t stream) {
    const float* x = (const float*)d_in[0];
    const void* ei = d_in[1];
    const float* W1 = (const float*)d_in[2];
    const float* b1 = (const float*)d_in[3];
    const float* W2 = (const float*)d_in[4];
    const float* b2 = (const float*)d_in[5];
    float* out = (float*)d_out;

    int N = in_sizes[0] / 128;
    int E = in_sizes[1] / 2;
    int NB = (N + (1 << SHIFT) - 1) >> SHIFT;        // buckets used (<= 256)
    int cap = ((2 * (E / NB)) / 256 + 2) * 256;      // 2x mean: safe for random input

    char* p = (char*)d_ws;
    unsigned* hs_u = (unsigned*)p;  p += (size_t)N * 32 * sizeof(unsigned);
    float* hs2 = (float*)p;         p += (size_t)N * sizeof(float);
    int* offs = (int*)p;            p += (size_t)N * sizeof(int);
    int* deg = (int*)p;             p += (size_t)N * sizeof(int);
    unsigned* pairs = (unsigned*)p; p += (size_t)NB * cap * sizeof(unsigned);
    int* csr = (int*)p;             p += (size_t)NB * cap * sizeof(int);
    int* gcursor = (int*)p;         p += 256 * sizeof(int);

    hipMemsetAsync(gcursor, 0, 256 * sizeof(int), stream);
    binA_kernel<<<512, 256, 0, stream>>>(ei, gcursor, pairs, E, cap);
    binB_kernel<<<NB, 256, 0, stream>>>(pairs, gcursor, csr, offs, deg, N, cap);
    gemm1_kernel<<<(N + 63) / 64, 256, 0, stream>>>(x, W1, deg, hs_u, N);
    pull1_kernel<<<((size_t)N * 64 + 255) / 256, 256, 0, stream>>>(
        (const uint4*)hs_u, offs, deg, csr, b1, W2, hs2, N);
    pull2_kernel<<<(N + 255) / 256, 256, 0, stream>>>(hs2, offs, deg, csr, b2, out, N);
}

// Round 6
// 198.961 us; speedup vs baseline: 2.3030x; 1.1363x over previous
//
#include <hip/hip_runtime.h>
#include <hip/hip_bf16.h>

// GCN 2-layer forward, R6 (R5 + compile fixes).
//   binA   : bucket-bin packed (row<<9|col&511) u32, relative global cursors
//   binB   : per-bucket count+scan+scatter -> padded CSR + offs/deg arrays
//   gemm1  : MFMA 16x16x32 bf16 split-precision (AhBh+AhBl+AlBh), W1 transposed
//            hi/lo in swizzled LDS, A-frags straight from global f32 x.
//   pull1  : one octet (8 lanes) per node; direct csr loads, 8-deep b128 pipeline,
//            float2/pk accumulate; fused bias+ReLU+W2-dot.
//   pull2  : out[j] = dinv*(sum hs2) + b2

#define SHIFT 9
#define BMASK ((1 << SHIFT) - 1)

typedef __attribute__((ext_vector_type(8))) short bf16x8;
typedef __attribute__((ext_vector_type(4))) float f32x4;

__device__ __forceinline__ bool detect_i64(const unsigned* u) {
    unsigned acc = 0;
#pragma unroll
    for (int i = 1; i <= 32; ++i) acc |= u[2 * i + 1];
    return acc == 0u;
}

__device__ __forceinline__ int load_edge(const void* ei, bool is64, long long idx) {
    if (is64) return ((const int*)ei)[idx << 1];  // low dword of little-endian i64
    return ((const int*)ei)[idx];
}

__device__ __forceinline__ unsigned bf16_rn(float x) {
    unsigned u = __float_as_uint(x);
    return (u + 0x7fffu + ((u >> 16) & 1u)) >> 16;
}
__device__ __forceinline__ unsigned pack_bf2(float a, float b) {
    return bf16_rn(a) | (bf16_rn(b) << 16);
}
__device__ __forceinline__ float bflo(unsigned v) { return __uint_as_float(v << 16); }
__device__ __forceinline__ float bfhi(unsigned v) {
    return __uint_as_float(v & 0xffff0000u);
}

__global__ __launch_bounds__(256) void binA_kernel(const void* ei, int* gcursor,
                                                   unsigned* __restrict__ pairs, int E,
                                                   int cap) {
    bool is64 = detect_i64((const unsigned*)ei);
    __shared__ int whist[4][256];
    __shared__ int bcur[256];
    int t = threadIdx.x;
    int wid = t >> 6;
    long long per = ((long long)E + gridDim.x - 1) / gridDim.x;
    long long e0 = (long long)blockIdx.x * per;
    long long e1 = e0 + per;
    if (e1 > E) e1 = E;
    whist[0][t] = 0; whist[1][t] = 0; whist[2][t] = 0; whist[3][t] = 0;
    __syncthreads();
    for (long long e = e0 + t; e < e1; e += 256) {
        int c = load_edge(ei, is64, (long long)E + e);
        atomicAdd(&whist[wid][c >> SHIFT], 1);
    }
    __syncthreads();
    int tot = whist[0][t] + whist[1][t] + whist[2][t] + whist[3][t];
    int rel = tot ? atomicAdd(&gcursor[t], tot) : 0;
    bcur[t] = t * cap + rel;
    __syncthreads();
    for (long long e = e0 + t; e < e1; e += 256) {
        int r = load_edge(ei, is64, e);
        int c = load_edge(ei, is64, (long long)E + e);
        int b = c >> SHIFT;
        int rk = atomicAdd(&bcur[b], 1);
        pairs[rk] = ((unsigned)r << SHIFT) | (unsigned)(c & BMASK);
    }
}

__global__ __launch_bounds__(256) void binB_kernel(const unsigned* __restrict__ pairs,
                                                   const int* __restrict__ gcursor,
                                                   int* __restrict__ csr,
                                                   int* __restrict__ offs,
                                                   int* __restrict__ deg, int N,
                                                   int cap) {
    __shared__ int cnt[1 << SHIFT];
    __shared__ int cur[1 << SHIFT];
    __shared__ int tmp[256];
    int b = blockIdx.x, t = threadIdx.x;
    int start = b * cap, end = b * cap + gcursor[b];
    cnt[t] = 0;
    cnt[t + 256] = 0;
    __syncthreads();
    for (int i = start + t; i < end; i += 256) atomicAdd(&cnt[pairs[i] & BMASK], 1);
    __syncthreads();
    int c0 = cnt[2 * t], c1 = cnt[2 * t + 1];
    int s = c0 + c1;
    tmp[t] = s;
    __syncthreads();
    for (int off = 1; off < 256; off <<= 1) {
        int xv = (t >= off) ? tmp[t - off] : 0;
        __syncthreads();
        tmp[t] += xv;
        __syncthreads();
    }
    int excl = tmp[t] - s;
    int p0 = start + excl;
    int p1 = p0 + c0;
    cur[2 * t] = p0;
    cur[2 * t + 1] = p1;
    int node0 = (b << SHIFT) + 2 * t;
    if (node0 < N) { offs[node0] = p0; deg[node0] = c0; }
    if (node0 + 1 < N) { offs[node0 + 1] = p1; deg[node0 + 1] = c1; }
    __syncthreads();
    for (int i = start + t; i < end; i += 256) {
        unsigned p = pairs[i];
        int pos = atomicAdd(&cur[p & BMASK], 1);
        csr[pos] = (int)(p >> SHIFT);
    }
}

// ---------------- gemm1: MFMA bf16-split ----------------
// Block: 256 thr (4 waves), 64 rows, 64 cols. Wave w: rows row0+w*16..+15.
// LDS: Wt_hi/Wt_lo transposed [64 cols][128 k] bf16, 16B-chunk XOR swizzle
//      (chunk' = chunk ^ (col&15)); reused as epilogue transpose buffer.
__global__ __launch_bounds__(256) void gemm1_kernel(const float* __restrict__ x,
                                                    const float* __restrict__ W1,
                                                    const int* __restrict__ deg,
                                                    unsigned* __restrict__ hs_u, int N) {
    __shared__ alignas(16) char smem[32768];
    char* wt_hi = smem;            // 16 KB
    char* wt_lo = smem + 16384;    // 16 KB
    int t = threadIdx.x;
    int l = t & 63;
    int w = t >> 6;

    // Stage W1 -> transposed hi/lo LDS (coalesced reads; swizzle spreads banks).
#pragma unroll
    for (int i = 0; i < 32; ++i) {
        int idx = t + 256 * i;     // 0..8191
        int k = idx >> 6;
        int c = idx & 63;
        float f = W1[idx];
        unsigned uh = bf16_rn(f);
        float fh = __uint_as_float(uh << 16);
        unsigned ul = bf16_rn(f - fh);
        int byte = c * 256 + (((k >> 3) ^ (c & 15)) << 4) + ((k & 7) << 1);
        *(unsigned short*)(wt_hi + byte) = (unsigned short)uh;
        *(unsigned short*)(wt_lo + byte) = (unsigned short)ul;
    }
    __syncthreads();

    int row0 = blockIdx.x * 64 + w * 16;
    int arow = row0 + (l & 15);
    bool rok = arow < N;
    const f32x4* x4 = (const f32x4*)x;

    f32x4 acc[4];
#pragma unroll
    for (int ct = 0; ct < 4; ++ct) acc[ct] = (f32x4)(0.f);

#pragma unroll
    for (int ks = 0; ks < 4; ++ks) {
        int kbase = ks * 32 + (l >> 4) * 8;
        // A fragment: x[arow][kbase..kbase+7] f32 -> bf16 hi/lo
        f32x4 xa = (f32x4)(0.f), xb = (f32x4)(0.f);
        if (rok) {
            xa = x4[(size_t)arow * 32 + (kbase >> 2)];
            xb = x4[(size_t)arow * 32 + (kbase >> 2) + 1];
        }
        unsigned ah[4], al[4];
#pragma unroll
        for (int j = 0; j < 4; ++j) {
            float f0 = (j < 2) ? ((j == 0) ? xa.x : xa.z) : ((j == 2) ? xb.x : xb.z);
            float f1 = (j < 2) ? ((j == 0) ? xa.y : xa.w) : ((j == 2) ? xb.y : xb.w);
            unsigned h0 = bf16_rn(f0), h1 = bf16_rn(f1);
            float r0 = f0 - __uint_as_float(h0 << 16);
            float r1 = f1 - __uint_as_float(h1 << 16);
            ah[j] = h0 | (h1 << 16);
            al[j] = bf16_rn(r0) | (bf16_rn(r1) << 16);
        }
        bf16x8 Ah, Al;
        ((unsigned*)&Ah)[0] = ah[0]; ((unsigned*)&Ah)[1] = ah[1];
        ((unsigned*)&Ah)[2] = ah[2]; ((unsigned*)&Ah)[3] = ah[3];
        ((unsigned*)&Al)[0] = al[0]; ((unsigned*)&Al)[1] = al[1];
        ((unsigned*)&Al)[2] = al[2]; ((unsigned*)&Al)[3] = al[3];
        int chunk = ks * 4 + (l >> 4);
#pragma unroll
        for (int ct = 0; ct < 4; ++ct) {
            int col = ct * 16 + (l & 15);
            int byte = col * 256 + ((chunk ^ (col & 15)) << 4);
            bf16x8 Bh = *(const bf16x8*)(wt_hi + byte);
            bf16x8 Bl = *(const bf16x8*)(wt_lo + byte);
            acc[ct] = __builtin_amdgcn_mfma_f32_16x16x32_bf16(Ah, Bh, acc[ct], 0, 0, 0);
            acc[ct] = __builtin_amdgcn_mfma_f32_16x16x32_bf16(Ah, Bl, acc[ct], 0, 0, 0);
            acc[ct] = __builtin_amdgcn_mfma_f32_16x16x32_bf16(Al, Bh, acc[ct], 0, 0, 0);
        }
    }

    // Epilogue: transpose via LDS (reuse W region), scale by dinv, pack bf16 pairs.
    __syncthreads();  // all waves done reading Wt
    float* hsb = (float*)(smem) + w * 16 * 68;  // [16 rows][68 cols]
#pragma unroll
    for (int ct = 0; ct < 4; ++ct) {
#pragma unroll
        for (int i = 0; i < 4; ++i) {
            int row = (l >> 4) * 4 + i;
            hsb[row * 68 + ct * 16 + (l & 15)] = acc[ct][i];
        }
    }
    __syncthreads();
    // lane l: row = l&15, quarter q = l>>4 -> feats q*16..q*16+15
    int row = l & 15;
    int q = l >> 4;
    int gr = row0 + row;
    if (gr < N) {
        float dinv = rsqrtf((float)deg[gr] + 1.0f);
        const f32x4* src = (const f32x4*)(hsb + row * 68 + q * 16);
        f32x4 f0 = src[0], f1 = src[1], f2 = src[2], f3 = src[3];
        uint4 o0, o1;
        o0.x = pack_bf2(f0.x * dinv, f0.y * dinv);
        o0.y = pack_bf2(f0.z * dinv, f0.w * dinv);
        o0.z = pack_bf2(f1.x * dinv, f1.y * dinv);
        o0.w = pack_bf2(f1.z * dinv, f1.w * dinv);
        o1.x = pack_bf2(f2.x * dinv, f2.y * dinv);
        o1.y = pack_bf2(f2.z * dinv, f2.w * dinv);
        o1.z = pack_bf2(f3.x * dinv, f3.y * dinv);
        o1.w = pack_bf2(f3.z * dinv, f3.w * dinv);
        uint4* dst = (uint4*)&hs_u[(size_t)gr * 32 + q * 8];
        dst[0] = o0;
        dst[1] = o1;
    }
}

// ---------------- pull1: octet-per-node ----------------
#define ACCV(v)                                            \
    {                                                      \
        float2 t0 = make_float2(bflo((v).x), bfhi((v).x)); \
        float2 t1 = make_float2(bflo((v).y), bfhi((v).y)); \
        float2 t2 = make_float2(bflo((v).z), bfhi((v).z)); \
        float2 t3 = make_float2(bflo((v).w), bfhi((v).w)); \
        a0.x += t0.x; a0.y += t0.y;                        \
        a1.x += t1.x; a1.y += t1.y;                        \
        a2.x += t2.x; a2.y += t2.y;                        \
        a3.x += t3.x; a3.y += t3.y;                        \
    }

__global__ __launch_bounds__(256) void pull1_kernel(
    const uint4* __restrict__ hs4, const int* __restrict__ offs,
    const int* __restrict__ deg, const int* __restrict__ csr,
    const float* __restrict__ b1, const float* __restrict__ W2,
    float* __restrict__ hs2, int N) {
    int gid = blockIdx.x * blockDim.x + threadIdx.x;
    int w = gid >> 3;  // node (one octet per node)
    if (w >= N) return;
    int lane = threadIdx.x & 63;
    int k = lane & 7;  // feat chunk: feats 8k..8k+7
    int s = offs[w];
    int cnt = deg[w];
    float dinv = rsqrtf((float)cnt + 1.0f);
    float2 a0 = make_float2(0.f, 0.f), a1 = a0, a2 = a0, a3 = a0;
    {  // self-loop
        uint4 v = hs4[(size_t)w * 8 + k];
        ACCV(v);
    }
    int e = 0;
    for (; e + 8 <= cnt; e += 8) {
        int r0 = csr[s + e + 0];
        int r1 = csr[s + e + 1];
        int r2 = csr[s + e + 2];
        int r3 = csr[s + e + 3];
        int r4 = csr[s + e + 4];
        int r5 = csr[s + e + 5];
        int r6 = csr[s + e + 6];
        int r7 = csr[s + e + 7];
        uint4 v0 = hs4[(size_t)r0 * 8 + k];
        uint4 v1 = hs4[(size_t)r1 * 8 + k];
        uint4 v2 = hs4[(size_t)r2 * 8 + k];
        uint4 v3 = hs4[(size_t)r3 * 8 + k];
        uint4 v4 = hs4[(size_t)r4 * 8 + k];
        uint4 v5 = hs4[(size_t)r5 * 8 + k];
        uint4 v6 = hs4[(size_t)r6 * 8 + k];
        uint4 v7 = hs4[(size_t)r7 * 8 + k];
        ACCV(v0); ACCV(v1); ACCV(v2); ACCV(v3);
        ACCV(v4); ACCV(v5); ACCV(v6); ACCV(v7);
    }
    for (; e < cnt; ++e) {
        int r = csr[s + e];
        uint4 v = hs4[(size_t)r * 8 + k];
        ACCV(v);
    }
    float4 bA = ((const float4*)b1)[2 * k];
    float4 bB = ((const float4*)b1)[2 * k + 1];
    float4 wA = ((const float4*)W2)[2 * k];
    float4 wB = ((const float4*)W2)[2 * k + 1];
    float p = fmaxf(fmaf(dinv, a0.x, bA.x), 0.f) * wA.x
            + fmaxf(fmaf(dinv, a0.y, bA.y), 0.f) * wA.y
            + fmaxf(fmaf(dinv, a1.x, bA.z), 0.f) * wA.z
            + fmaxf(fmaf(dinv, a1.y, bA.w), 0.f) * wA.w
            + fmaxf(fmaf(dinv, a2.x, bB.x), 0.f) * wB.x
            + fmaxf(fmaf(dinv, a2.y, bB.y), 0.f) * wB.y
            + fmaxf(fmaf(dinv, a3.x, bB.z), 0.f) * wB.z
            + fmaxf(fmaf(dinv, a3.y, bB.w), 0.f) * wB.w;
    p += __shfl_xor(p, 1);
    p += __shfl_xor(p, 2);
    p += __shfl_xor(p, 4);
    if ((lane & 7) == 0) hs2[w] = dinv * p;
}

__global__ __launch_bounds__(256) void pull2_kernel(
    const float* __restrict__ hs2, const int* __restrict__ offs,
    const int* __restrict__ deg, const int* __restrict__ csr,
    const float* __restrict__ b2, float* __restrict__ out, int N) {
    int i = blockIdx.x * blockDim.x + threadIdx.x;
    if (i >= N) return;
    int s = offs[i];
    int cnt = deg[i];
    float dinv = rsqrtf((float)cnt + 1.0f);
    float a0 = hs2[i];  // self-loop
    float a1 = 0.f, a2 = 0.f, a3 = 0.f;
    int kk = 0;
    for (; kk + 4 <= cnt; kk += 4) {
        a0 += hs2[csr[s + kk]];
        a1 += hs2[csr[s + kk + 1]];
        a2 += hs2[csr[s + kk + 2]];
        a3 += hs2[csr[s + kk + 3]];
    }
    for (; kk < cnt; ++kk) a0 += hs2[csr[s + kk]];
    out[i] = fmaf(dinv, (a0 + a1) + (a2 + a3), b2[0]);
}

extern "C" void kernel_launch(void* const* d_in, const int* in_sizes, int n_in,
                              void* d_out, int out_size, void* d_ws, size_t ws_size,
                              hipStream_t stream) {
    const float* x = (const float*)d_in[0];
    const void* ei = d_in[1];
    const float* W1 = (const float*)d_in[2];
    const float* b1 = (const float*)d_in[3];
    const float* W2 = (const float*)d_in[4];
    const float* b2 = (const float*)d_in[5];
    float* out = (float*)d_out;

    int N = in_sizes[0] / 128;
    int E = in_sizes[1] / 2;
    int NB = (N + (1 << SHIFT) - 1) >> SHIFT;
    int cap = ((2 * (E / NB)) / 256 + 2) * 256;

    char* p = (char*)d_ws;
    unsigned* hs_u = (unsigned*)p;  p += (size_t)N * 32 * sizeof(unsigned);
    float* hs2 = (float*)p;         p += (size_t)N * sizeof(float);
    int* offs = (int*)p;            p += (size_t)N * sizeof(int);
    int* deg = (int*)p;             p += (size_t)N * sizeof(int);
    unsigned* pairs = (unsigned*)p; p += (size_t)NB * cap * sizeof(unsigned);
    int* csr = (int*)p;             p += (size_t)NB * cap * sizeof(int);
    int* gcursor = (int*)p;         p += 256 * sizeof(int);

    (void)hipMemsetAsync(gcursor, 0, 256 * sizeof(int), stream);
    binA_kernel<<<512, 256, 0, stream>>>(ei, gcursor, pairs, E, cap);
    binB_kernel<<<NB, 256, 0, stream>>>(pairs, gcursor, csr, offs, deg, N, cap);
    gemm1_kernel<<<(N + 63) / 64, 256, 0, stream>>>(x, W1, deg, hs_u, N);
    pull1_kernel<<<((size_t)N * 8 + 255) / 256, 256, 0, stream>>>(
        (const uint4*)hs_u, offs, deg, csr, b1, W2, hs2, N);
    pull2_kernel<<<(N + 255) / 256, 256, 0, stream>>>(hs2, offs, deg, csr, b2, out, N);
}

// Round 7
// 192.771 us; speedup vs baseline: 2.3769x; 1.0321x over previous
//
#include <hip/hip_runtime.h>
#include <hip/hip_bf16.h>

// GCN 2-layer forward, R7.
//   binA   : single-read pass (register-cached packed edges), bucket-bin u32 pairs
//   binB   : SHIFT=8 -> 391 blocks, 256-node window, 1 node/thread count+scan+scatter
//   gemm1  : MFMA 16x16x32 bf16 split-precision (AhBh+AhBl+AlBh)
//   pull1  : one octet (8 lanes) per node; direct csr loads, float2 accumulate
//   pull2  : out[j] = dinv*(sum hs2) + b2, 8-deep ILP

#define SHIFT 8
#define BMASK ((1 << SHIFT) - 1)
#define MAXB 512

typedef __attribute__((ext_vector_type(8))) short bf16x8;
typedef __attribute__((ext_vector_type(4))) float f32x4;

__device__ __forceinline__ bool detect_i64(const unsigned* u) {
    unsigned acc = 0;
#pragma unroll
    for (int i = 1; i <= 32; ++i) acc |= u[2 * i + 1];
    return acc == 0u;
}

__device__ __forceinline__ int load_edge(const void* ei, bool is64, long long idx) {
    if (is64) return ((const int*)ei)[idx << 1];  // low dword of little-endian i64
    return ((const int*)ei)[idx];
}

__device__ __forceinline__ unsigned bf16_rn(float x) {
    unsigned u = __float_as_uint(x);
    return (u + 0x7fffu + ((u >> 16) & 1u)) >> 16;
}
__device__ __forceinline__ unsigned pack_bf2(float a, float b) {
    return bf16_rn(a) | (bf16_rn(b) << 16);
}
__device__ __forceinline__ float bflo(unsigned v) { return __uint_as_float(v << 16); }
__device__ __forceinline__ float bfhi(unsigned v) {
    return __uint_as_float(v & 0xffff0000u);
}

__global__ __launch_bounds__(256) void binA_kernel(const void* ei, int* gcursor,
                                                   unsigned* __restrict__ pairs, int E,
                                                   int cap, int NB) {
    bool is64 = detect_i64((const unsigned*)ei);
    __shared__ int whist[4][MAXB];
    __shared__ int bcur[MAXB];
    int t = threadIdx.x;
    int wid = t >> 6;
    long long per = ((long long)E + gridDim.x - 1) / gridDim.x;
    long long e0 = (long long)blockIdx.x * per;
    long long e1 = e0 + per;
    if (e1 > E) e1 = E;
    for (int b = t; b < NB; b += 256) {
        whist[0][b] = 0; whist[1][b] = 0; whist[2][b] = 0; whist[3][b] = 0;
    }
    __syncthreads();
    unsigned pk[16];
    int bs[16];
    int i = 0;
    for (long long e = e0 + t; e < e1; e += 256, ++i) {
        int r = load_edge(ei, is64, e);
        int c = load_edge(ei, is64, (long long)E + e);
        int b = c >> SHIFT;
        unsigned p = ((unsigned)r << SHIFT) | (unsigned)(c & BMASK);
        atomicAdd(&whist[wid][b], 1);
        if (i < 16) { pk[i] = p; bs[i] = b; }
    }
    __syncthreads();
    for (int b = t; b < NB; b += 256) {
        int tot = whist[0][b] + whist[1][b] + whist[2][b] + whist[3][b];
        int rel = tot ? atomicAdd(&gcursor[b], tot) : 0;
        bcur[b] = b * cap + rel;
    }
    __syncthreads();
    i = 0;
    for (long long e = e0 + t; e < e1; e += 256, ++i) {
        unsigned p;
        int b;
        if (i < 16) {
            p = pk[i];
            b = bs[i];
        } else {
            int r = load_edge(ei, is64, e);
            int c = load_edge(ei, is64, (long long)E + e);
            b = c >> SHIFT;
            p = ((unsigned)r << SHIFT) | (unsigned)(c & BMASK);
        }
        int rk = atomicAdd(&bcur[b], 1);
        pairs[rk] = p;
    }
}

__global__ __launch_bounds__(256) void binB_kernel(const unsigned* __restrict__ pairs,
                                                   const int* __restrict__ gcursor,
                                                   int* __restrict__ csr,
                                                   int* __restrict__ offs,
                                                   int* __restrict__ deg, int N,
                                                   int cap) {
    __shared__ int cnt[256];
    __shared__ int cur[256];
    __shared__ int tmp[256];
    int b = blockIdx.x, t = threadIdx.x;
    int start = b * cap, end = start + gcursor[b];
    cnt[t] = 0;
    __syncthreads();
    for (int i = start + t; i < end; i += 256) atomicAdd(&cnt[pairs[i] & BMASK], 1);
    __syncthreads();
    int c0 = cnt[t];
    tmp[t] = c0;
    __syncthreads();
    for (int off = 1; off < 256; off <<= 1) {
        int xv = (t >= off) ? tmp[t - off] : 0;
        __syncthreads();
        tmp[t] += xv;
        __syncthreads();
    }
    int p0 = start + tmp[t] - c0;
    cur[t] = p0;
    int node = (b << SHIFT) + t;
    if (node < N) {
        offs[node] = p0;
        deg[node] = c0;
    }
    __syncthreads();
    for (int i = start + t; i < end; i += 256) {
        unsigned p = pairs[i];
        int pos = atomicAdd(&cur[p & BMASK], 1);
        csr[pos] = (int)(p >> SHIFT);
    }
}

// ---------------- gemm1: MFMA bf16-split ----------------
__global__ __launch_bounds__(256) void gemm1_kernel(const float* __restrict__ x,
                                                    const float* __restrict__ W1,
                                                    const int* __restrict__ deg,
                                                    unsigned* __restrict__ hs_u, int N) {
    __shared__ alignas(16) char smem[32768];
    char* wt_hi = smem;            // 16 KB
    char* wt_lo = smem + 16384;    // 16 KB
    int t = threadIdx.x;
    int l = t & 63;
    int w = t >> 6;

#pragma unroll
    for (int i = 0; i < 32; ++i) {
        int idx = t + 256 * i;     // 0..8191
        int k = idx >> 6;
        int c = idx & 63;
        float f = W1[idx];
        unsigned uh = bf16_rn(f);
        float fh = __uint_as_float(uh << 16);
        unsigned ul = bf16_rn(f - fh);
        int byte = c * 256 + (((k >> 3) ^ (c & 15)) << 4) + ((k & 7) << 1);
        *(unsigned short*)(wt_hi + byte) = (unsigned short)uh;
        *(unsigned short*)(wt_lo + byte) = (unsigned short)ul;
    }
    __syncthreads();

    int row0 = blockIdx.x * 64 + w * 16;
    int arow = row0 + (l & 15);
    bool rok = arow < N;
    const f32x4* x4 = (const f32x4*)x;

    f32x4 acc[4];
#pragma unroll
    for (int ct = 0; ct < 4; ++ct) acc[ct] = (f32x4)(0.f);

#pragma unroll
    for (int ks = 0; ks < 4; ++ks) {
        int kbase = ks * 32 + (l >> 4) * 8;
        f32x4 xa = (f32x4)(0.f), xb = (f32x4)(0.f);
        if (rok) {
            xa = x4[(size_t)arow * 32 + (kbase >> 2)];
            xb = x4[(size_t)arow * 32 + (kbase >> 2) + 1];
        }
        unsigned ah[4], al[4];
#pragma unroll
        for (int j = 0; j < 4; ++j) {
            float f0 = (j < 2) ? ((j == 0) ? xa.x : xa.z) : ((j == 2) ? xb.x : xb.z);
            float f1 = (j < 2) ? ((j == 0) ? xa.y : xa.w) : ((j == 2) ? xb.y : xb.w);
            unsigned h0 = bf16_rn(f0), h1 = bf16_rn(f1);
            float r0 = f0 - __uint_as_float(h0 << 16);
            float r1 = f1 - __uint_as_float(h1 << 16);
            ah[j] = h0 | (h1 << 16);
            al[j] = bf16_rn(r0) | (bf16_rn(r1) << 16);
        }
        bf16x8 Ah, Al;
        ((unsigned*)&Ah)[0] = ah[0]; ((unsigned*)&Ah)[1] = ah[1];
        ((unsigned*)&Ah)[2] = ah[2]; ((unsigned*)&Ah)[3] = ah[3];
        ((unsigned*)&Al)[0] = al[0]; ((unsigned*)&Al)[1] = al[1];
        ((unsigned*)&Al)[2] = al[2]; ((unsigned*)&Al)[3] = al[3];
        int chunk = ks * 4 + (l >> 4);
#pragma unroll
        for (int ct = 0; ct < 4; ++ct) {
            int col = ct * 16 + (l & 15);
            int byte = col * 256 + ((chunk ^ (col & 15)) << 4);
            bf16x8 Bh = *(const bf16x8*)(wt_hi + byte);
            bf16x8 Bl = *(const bf16x8*)(wt_lo + byte);
            acc[ct] = __builtin_amdgcn_mfma_f32_16x16x32_bf16(Ah, Bh, acc[ct], 0, 0, 0);
            acc[ct] = __builtin_amdgcn_mfma_f32_16x16x32_bf16(Ah, Bl, acc[ct], 0, 0, 0);
            acc[ct] = __builtin_amdgcn_mfma_f32_16x16x32_bf16(Al, Bh, acc[ct], 0, 0, 0);
        }
    }

    __syncthreads();  // all waves done reading Wt
    float* hsb = (float*)(smem) + w * 16 * 68;  // [16 rows][68 cols]
#pragma unroll
    for (int ct = 0; ct < 4; ++ct) {
#pragma unroll
        for (int i = 0; i < 4; ++i) {
            int row = (l >> 4) * 4 + i;
            hsb[row * 68 + ct * 16 + (l & 15)] = acc[ct][i];
        }
    }
    __syncthreads();
    int row = l & 15;
    int q = l >> 4;
    int gr = row0 + row;
    if (gr < N) {
        float dinv = rsqrtf((float)deg[gr] + 1.0f);
        const f32x4* src = (const f32x4*)(hsb + row * 68 + q * 16);
        f32x4 f0 = src[0], f1 = src[1], f2 = src[2], f3 = src[3];
        uint4 o0, o1;
        o0.x = pack_bf2(f0.x * dinv, f0.y * dinv);
        o0.y = pack_bf2(f0.z * dinv, f0.w * dinv);
        o0.z = pack_bf2(f1.x * dinv, f1.y * dinv);
        o0.w = pack_bf2(f1.z * dinv, f1.w * dinv);
        o1.x = pack_bf2(f2.x * dinv, f2.y * dinv);
        o1.y = pack_bf2(f2.z * dinv, f2.w * dinv);
        o1.z = pack_bf2(f3.x * dinv, f3.y * dinv);
        o1.w = pack_bf2(f3.z * dinv, f3.w * dinv);
        uint4* dst = (uint4*)&hs_u[(size_t)gr * 32 + q * 8];
        dst[0] = o0;
        dst[1] = o1;
    }
}

// ---------------- pull1: octet-per-node ----------------
#define ACCV(v)                                            \
    {                                                      \
        float2 t0 = make_float2(bflo((v).x), bfhi((v).x)); \
        float2 t1 = make_float2(bflo((v).y), bfhi((v).y)); \
        float2 t2 = make_float2(bflo((v).z), bfhi((v).z)); \
        float2 t3 = make_float2(bflo((v).w), bfhi((v).w)); \
        a0.x += t0.x; a0.y += t0.y;                        \
        a1.x += t1.x; a1.y += t1.y;                        \
        a2.x += t2.x; a2.y += t2.y;                        \
        a3.x += t3.x; a3.y += t3.y;                        \
    }

__global__ __launch_bounds__(256) void pull1_kernel(
    const uint4* __restrict__ hs4, const int* __restrict__ offs,
    const int* __restrict__ deg, const int* __restrict__ csr,
    const float* __restrict__ b1, const float* __restrict__ W2,
    float* __restrict__ hs2, int N) {
    int gid = blockIdx.x * blockDim.x + threadIdx.x;
    int w = gid >> 3;  // node (one octet per node)
    if (w >= N) return;
    int lane = threadIdx.x & 63;
    int k = lane & 7;  // feat chunk: feats 8k..8k+7
    int s = offs[w];
    int cnt = deg[w];
    float dinv = rsqrtf((float)cnt + 1.0f);
    float2 a0 = make_float2(0.f, 0.f), a1 = a0, a2 = a0, a3 = a0;
    {  // self-loop
        uint4 v = hs4[(size_t)w * 8 + k];
        ACCV(v);
    }
    int e = 0;
    for (; e + 8 <= cnt; e += 8) {
        int r0 = csr[s + e + 0];
        int r1 = csr[s + e + 1];
        int r2 = csr[s + e + 2];
        int r3 = csr[s + e + 3];
        int r4 = csr[s + e + 4];
        int r5 = csr[s + e + 5];
        int r6 = csr[s + e + 6];
        int r7 = csr[s + e + 7];
        uint4 v0 = hs4[(size_t)r0 * 8 + k];
        uint4 v1 = hs4[(size_t)r1 * 8 + k];
        uint4 v2 = hs4[(size_t)r2 * 8 + k];
        uint4 v3 = hs4[(size_t)r3 * 8 + k];
        uint4 v4 = hs4[(size_t)r4 * 8 + k];
        uint4 v5 = hs4[(size_t)r5 * 8 + k];
        uint4 v6 = hs4[(size_t)r6 * 8 + k];
        uint4 v7 = hs4[(size_t)r7 * 8 + k];
        ACCV(v0); ACCV(v1); ACCV(v2); ACCV(v3);
        ACCV(v4); ACCV(v5); ACCV(v6); ACCV(v7);
    }
    for (; e < cnt; ++e) {
        int r = csr[s + e];
        uint4 v = hs4[(size_t)r * 8 + k];
        ACCV(v);
    }
    float4 bA = ((const float4*)b1)[2 * k];
    float4 bB = ((const float4*)b1)[2 * k + 1];
    float4 wA = ((const float4*)W2)[2 * k];
    float4 wB = ((const float4*)W2)[2 * k + 1];
    float p = fmaxf(fmaf(dinv, a0.x, bA.x), 0.f) * wA.x
            + fmaxf(fmaf(dinv, a0.y, bA.y), 0.f) * wA.y
            + fmaxf(fmaf(dinv, a1.x, bA.z), 0.f) * wA.z
            + fmaxf(fmaf(dinv, a1.y, bA.w), 0.f) * wA.w
            + fmaxf(fmaf(dinv, a2.x, bB.x), 0.f) * wB.x
            + fmaxf(fmaf(dinv, a2.y, bB.y), 0.f) * wB.y
            + fmaxf(fmaf(dinv, a3.x, bB.z), 0.f) * wB.z
            + fmaxf(fmaf(dinv, a3.y, bB.w), 0.f) * wB.w;
    p += __shfl_xor(p, 1);
    p += __shfl_xor(p, 2);
    p += __shfl_xor(p, 4);
    if ((lane & 7) == 0) hs2[w] = dinv * p;
}

__global__ __launch_bounds__(256) void pull2_kernel(
    const float* __restrict__ hs2, const int* __restrict__ offs,
    const int* __restrict__ deg, const int* __restrict__ csr,
    const float* __restrict__ b2, float* __restrict__ out, int N) {
    int i = blockIdx.x * blockDim.x + threadIdx.x;
    if (i >= N) return;
    int s = offs[i];
    int cnt = deg[i];
    float dinv = rsqrtf((float)cnt + 1.0f);
    float a0 = hs2[i];  // self-loop
    float a1 = 0.f, a2 = 0.f, a3 = 0.f;
    float a4 = 0.f, a5 = 0.f, a6 = 0.f, a7 = 0.f;
    int kk = 0;
    for (; kk + 8 <= cnt; kk += 8) {
        a0 += hs2[csr[s + kk]];
        a1 += hs2[csr[s + kk + 1]];
        a2 += hs2[csr[s + kk + 2]];
        a3 += hs2[csr[s + kk + 3]];
        a4 += hs2[csr[s + kk + 4]];
        a5 += hs2[csr[s + kk + 5]];
        a6 += hs2[csr[s + kk + 6]];
        a7 += hs2[csr[s + kk + 7]];
    }
    for (; kk < cnt; ++kk) a0 += hs2[csr[s + kk]];
    out[i] = fmaf(dinv, ((a0 + a1) + (a2 + a3)) + ((a4 + a5) + (a6 + a7)), b2[0]);
}

extern "C" void kernel_launch(void* const* d_in, const int* in_sizes, int n_in,
                              void* d_out, int out_size, void* d_ws, size_t ws_size,
                              hipStream_t stream) {
    const float* x = (const float*)d_in[0];
    const void* ei = d_in[1];
    const float* W1 = (const float*)d_in[2];
    const float* b1 = (const float*)d_in[3];
    const float* W2 = (const float*)d_in[4];
    const float* b2 = (const float*)d_in[5];
    float* out = (float*)d_out;

    int N = in_sizes[0] / 128;
    int E = in_sizes[1] / 2;
    int NB = (N + (1 << SHIFT) - 1) >> SHIFT;        // buckets (<= MAXB)
    int cap = ((2 * (E / NB)) / 256 + 2) * 256;      // 2x mean: safe for random input

    char* p = (char*)d_ws;
    unsigned* hs_u = (unsigned*)p;  p += (size_t)N * 32 * sizeof(unsigned);
    float* hs2 = (float*)p;         p += (size_t)N * sizeof(float);
    int* offs = (int*)p;            p += (size_t)N * sizeof(int);
    int* deg = (int*)p;             p += (size_t)N * sizeof(int);
    unsigned* pairs = (unsigned*)p; p += (size_t)NB * cap * sizeof(unsigned);
    int* csr = (int*)p;             p += (size_t)NB * cap * sizeof(int);
    int* gcursor = (int*)p;         p += MAXB * sizeof(int);

    (void)hipMemsetAsync(gcursor, 0, MAXB * sizeof(int), stream);
    binA_kernel<<<512, 256, 0, stream>>>(ei, gcursor, pairs, E, cap, NB);
    binB_kernel<<<NB, 256, 0, stream>>>(pairs, gcursor, csr, offs, deg, N, cap);
    gemm1_kernel<<<(N + 63) / 64, 256, 0, stream>>>(x, W1, deg, hs_u, N);
    pull1_kernel<<<((size_t)N * 8 + 255) / 256, 256, 0, stream>>>(
        (const uint4*)hs_u, offs, deg, csr, b1, W2, hs2, N);
    pull2_kernel<<<(N + 255) / 256, 256, 0, stream>>>(hs2, offs, deg, csr, b2, out, N);
}

// Round 8
// 188.044 us; speedup vs baseline: 2.4366x; 1.0251x over previous
//
#include <hip/hip_runtime.h>
#include <hip/hip_bf16.h>

// GCN 2-layer forward, R8.
//   fusedA : blocks [0,512): binA bucket-binning | blocks [512,..): UNSCALED MFMA gemm
//            (independent halves run concurrently; memory-bound ∥ compute-bound)
//   binB   : per-bucket count+scan+scatter -> CSR/offs/deg, PLUS dinv-rescale of its
//            own 256 hs rows (loads hoisted above the scan to hide latency)
//   pull1  : octet-per-node; per-lane csr load + shfl broadcast + prefetch
//   pull2  : out[j] = dinv*(sum hs2) + b2, 8-deep ILP

#define SHIFT 8
#define BMASK ((1 << SHIFT) - 1)
#define MAXB 512

typedef __attribute__((ext_vector_type(8))) short bf16x8;
typedef __attribute__((ext_vector_type(4))) float f32x4;

__device__ __forceinline__ bool detect_i64(const unsigned* u) {
    unsigned acc = 0;
#pragma unroll
    for (int i = 1; i <= 32; ++i) acc |= u[2 * i + 1];
    return acc == 0u;
}

__device__ __forceinline__ int load_edge(const void* ei, bool is64, long long idx) {
    if (is64) return ((const int*)ei)[idx << 1];  // low dword of little-endian i64
    return ((const int*)ei)[idx];
}

__device__ __forceinline__ unsigned bf16_rn(float x) {
    unsigned u = __float_as_uint(x);
    return (u + 0x7fffu + ((u >> 16) & 1u)) >> 16;
}
__device__ __forceinline__ unsigned pack_bf2(float a, float b) {
    return bf16_rn(a) | (bf16_rn(b) << 16);
}
__device__ __forceinline__ float bflo(unsigned v) { return __uint_as_float(v << 16); }
__device__ __forceinline__ float bfhi(unsigned v) {
    return __uint_as_float(v & 0xffff0000u);
}

__global__ __launch_bounds__(256) void fusedA_kernel(
    const void* ei, int* gcursor, unsigned* __restrict__ pairs, int E, int cap, int NB,
    const float* __restrict__ x, const float* __restrict__ W1,
    unsigned* __restrict__ hs_u, int N, int nAblk) {
    __shared__ alignas(16) char smem[32768];
    int t = threadIdx.x;
    if ((int)blockIdx.x < nAblk) {
        // ---------------- binA ----------------
        int* whist = (int*)smem;            // [4][MAXB]
        int* bcur = (int*)(smem + 8192);    // [MAXB]
        bool is64 = detect_i64((const unsigned*)ei);
        int wid = t >> 6;
        long long per = ((long long)E + nAblk - 1) / nAblk;
        long long e0 = (long long)blockIdx.x * per;
        long long e1 = e0 + per;
        if (e1 > E) e1 = E;
        for (int i = t; i < 4 * MAXB; i += 256) whist[i] = 0;
        __syncthreads();
        unsigned pk[16];
        int bs[16];
        int i = 0;
        for (long long e = e0 + t; e < e1; e += 256, ++i) {
            int r = load_edge(ei, is64, e);
            int c = load_edge(ei, is64, (long long)E + e);
            int b = c >> SHIFT;
            unsigned p = ((unsigned)r << SHIFT) | (unsigned)(c & BMASK);
            atomicAdd(&whist[wid * MAXB + b], 1);
            if (i < 16) { pk[i] = p; bs[i] = b; }
        }
        __syncthreads();
        for (int b = t; b < NB; b += 256) {
            int tot = whist[b] + whist[MAXB + b] + whist[2 * MAXB + b] +
                      whist[3 * MAXB + b];
            int rel = tot ? atomicAdd(&gcursor[b], tot) : 0;
            bcur[b] = b * cap + rel;
        }
        __syncthreads();
        i = 0;
        for (long long e = e0 + t; e < e1; e += 256, ++i) {
            unsigned p;
            int b;
            if (i < 16) {
                p = pk[i];
                b = bs[i];
            } else {
                int r = load_edge(ei, is64, e);
                int c = load_edge(ei, is64, (long long)E + e);
                b = c >> SHIFT;
                p = ((unsigned)r << SHIFT) | (unsigned)(c & BMASK);
            }
            int rk = atomicAdd(&bcur[b], 1);
            pairs[rk] = p;
        }
    } else {
        // ---------------- gemm (unscaled) ----------------
        char* wt_hi = smem;            // 16 KB
        char* wt_lo = smem + 16384;    // 16 KB
        int l = t & 63;
        int w = t >> 6;
#pragma unroll
        for (int i = 0; i < 32; ++i) {
            int idx = t + 256 * i;     // 0..8191
            int k = idx >> 6;
            int c = idx & 63;
            float f = W1[idx];
            unsigned uh = bf16_rn(f);
            float fh = __uint_as_float(uh << 16);
            unsigned ul = bf16_rn(f - fh);
            int byte = c * 256 + (((k >> 3) ^ (c & 15)) << 4) + ((k & 7) << 1);
            *(unsigned short*)(wt_hi + byte) = (unsigned short)uh;
            *(unsigned short*)(wt_lo + byte) = (unsigned short)ul;
        }
        __syncthreads();
        int row0 = ((int)blockIdx.x - nAblk) * 64 + w * 16;
        int arow = row0 + (l & 15);
        bool rok = arow < N;
        const f32x4* x4 = (const f32x4*)x;
        f32x4 acc[4];
#pragma unroll
        for (int ct = 0; ct < 4; ++ct) acc[ct] = (f32x4)(0.f);
#pragma unroll
        for (int ks = 0; ks < 4; ++ks) {
            int kbase = ks * 32 + (l >> 4) * 8;
            f32x4 xa = (f32x4)(0.f), xb = (f32x4)(0.f);
            if (rok) {
                xa = x4[(size_t)arow * 32 + (kbase >> 2)];
                xb = x4[(size_t)arow * 32 + (kbase >> 2) + 1];
            }
            unsigned ah[4], al[4];
#pragma unroll
            for (int j = 0; j < 4; ++j) {
                float f0 = (j < 2) ? ((j == 0) ? xa.x : xa.z)
                                   : ((j == 2) ? xb.x : xb.z);
                float f1 = (j < 2) ? ((j == 0) ? xa.y : xa.w)
                                   : ((j == 2) ? xb.y : xb.w);
                unsigned h0 = bf16_rn(f0), h1 = bf16_rn(f1);
                float r0 = f0 - __uint_as_float(h0 << 16);
                float r1 = f1 - __uint_as_float(h1 << 16);
                ah[j] = h0 | (h1 << 16);
                al[j] = bf16_rn(r0) | (bf16_rn(r1) << 16);
            }
            bf16x8 Ah, Al;
            ((unsigned*)&Ah)[0] = ah[0]; ((unsigned*)&Ah)[1] = ah[1];
            ((unsigned*)&Ah)[2] = ah[2]; ((unsigned*)&Ah)[3] = ah[3];
            ((unsigned*)&Al)[0] = al[0]; ((unsigned*)&Al)[1] = al[1];
            ((unsigned*)&Al)[2] = al[2]; ((unsigned*)&Al)[3] = al[3];
            int chunk = ks * 4 + (l >> 4);
#pragma unroll
            for (int ct = 0; ct < 4; ++ct) {
                int col = ct * 16 + (l & 15);
                int byte = col * 256 + ((chunk ^ (col & 15)) << 4);
                bf16x8 Bh = *(const bf16x8*)(wt_hi + byte);
                bf16x8 Bl = *(const bf16x8*)(wt_lo + byte);
                acc[ct] =
                    __builtin_amdgcn_mfma_f32_16x16x32_bf16(Ah, Bh, acc[ct], 0, 0, 0);
                acc[ct] =
                    __builtin_amdgcn_mfma_f32_16x16x32_bf16(Ah, Bl, acc[ct], 0, 0, 0);
                acc[ct] =
                    __builtin_amdgcn_mfma_f32_16x16x32_bf16(Al, Bh, acc[ct], 0, 0, 0);
            }
        }
        __syncthreads();  // all waves done reading Wt
        float* hsb = (float*)(smem) + w * 16 * 68;  // [16 rows][68 cols]
#pragma unroll
        for (int ct = 0; ct < 4; ++ct) {
#pragma unroll
            for (int i = 0; i < 4; ++i) {
                int row = (l >> 4) * 4 + i;
                hsb[row * 68 + ct * 16 + (l & 15)] = acc[ct][i];
            }
        }
        __syncthreads();
        int row = l & 15;
        int q = l >> 4;
        int gr = row0 + row;
        if (gr < N) {
            const f32x4* src = (const f32x4*)(hsb + row * 68 + q * 16);
            f32x4 f0 = src[0], f1 = src[1], f2 = src[2], f3 = src[3];
            uint4 o0, o1;
            o0.x = pack_bf2(f0.x, f0.y);
            o0.y = pack_bf2(f0.z, f0.w);
            o0.z = pack_bf2(f1.x, f1.y);
            o0.w = pack_bf2(f1.z, f1.w);
            o1.x = pack_bf2(f2.x, f2.y);
            o1.y = pack_bf2(f2.z, f2.w);
            o1.z = pack_bf2(f3.x, f3.y);
            o1.w = pack_bf2(f3.z, f3.w);
            uint4* dst = (uint4*)&hs_u[(size_t)gr * 32 + q * 8];
            dst[0] = o0;
            dst[1] = o1;
        }
    }
}

__global__ __launch_bounds__(256) void binB_kernel(const unsigned* __restrict__ pairs,
                                                   const int* __restrict__ gcursor,
                                                   int* __restrict__ csr,
                                                   int* __restrict__ offs,
                                                   int* __restrict__ deg,
                                                   unsigned* __restrict__ hs_u, int N,
                                                   int cap) {
    __shared__ int cnt[256];
    __shared__ int cur[256];
    __shared__ int tmp[256];
    int b = blockIdx.x, t = threadIdx.x;
    int start = b * cap, end = start + gcursor[b];
    cnt[t] = 0;
    __syncthreads();
    for (int i = start + t; i < end; i += 256) atomicAdd(&cnt[pairs[i] & BMASK], 1);
    __syncthreads();
    int c0 = cnt[t];
    int node = (b << SHIFT) + t;
    bool nok = node < N;
    // hoist hs row loads (scale phase) above the scan to hide global latency
    uint4 hv[8];
    if (nok) {
        const uint4* src = (const uint4*)&hs_u[(size_t)node * 32];
#pragma unroll
        for (int i = 0; i < 8; ++i) hv[i] = src[i];
    }
    tmp[t] = c0;
    __syncthreads();
    for (int off = 1; off < 256; off <<= 1) {
        int xv = (t >= off) ? tmp[t - off] : 0;
        __syncthreads();
        tmp[t] += xv;
        __syncthreads();
    }
    int p0 = start + tmp[t] - c0;
    cur[t] = p0;
    if (nok) {
        offs[node] = p0;
        deg[node] = c0;
        float dv = rsqrtf((float)c0 + 1.0f);
        uint4* dst = (uint4*)&hs_u[(size_t)node * 32];
#pragma unroll
        for (int i = 0; i < 8; ++i) {
            uint4 v = hv[i];
            v.x = pack_bf2(bflo(v.x) * dv, bfhi(v.x) * dv);
            v.y = pack_bf2(bflo(v.y) * dv, bfhi(v.y) * dv);
            v.z = pack_bf2(bflo(v.z) * dv, bfhi(v.z) * dv);
            v.w = pack_bf2(bflo(v.w) * dv, bfhi(v.w) * dv);
            dst[i] = v;
        }
    }
    __syncthreads();
    for (int i = start + t; i < end; i += 256) {
        unsigned p = pairs[i];
        int pos = atomicAdd(&cur[p & BMASK], 1);
        csr[pos] = (int)(p >> SHIFT);
    }
}

// ---------------- pull1: octet-per-node, per-lane csr + shfl + prefetch ------
#define ACCV(v)                                            \
    {                                                      \
        float2 t0 = make_float2(bflo((v).x), bfhi((v).x)); \
        float2 t1 = make_float2(bflo((v).y), bfhi((v).y)); \
        float2 t2 = make_float2(bflo((v).z), bfhi((v).z)); \
        float2 t3 = make_float2(bflo((v).w), bfhi((v).w)); \
        a0.x += t0.x; a0.y += t0.y;                        \
        a1.x += t1.x; a1.y += t1.y;                        \
        a2.x += t2.x; a2.y += t2.y;                        \
        a3.x += t3.x; a3.y += t3.y;                        \
    }

__global__ __launch_bounds__(256) void pull1_kernel(
    const uint4* __restrict__ hs4, const int* __restrict__ offs,
    const int* __restrict__ deg, const int* __restrict__ csr,
    const float* __restrict__ b1, const float* __restrict__ W2,
    float* __restrict__ hs2, int N) {
    int gid = blockIdx.x * blockDim.x + threadIdx.x;
    int w = gid >> 3;  // node (one octet per node)
    if (w >= N) return;
    int lane = threadIdx.x & 63;
    int k = lane & 7;       // feat chunk: feats 8k..8k+7
    int lane8 = lane & 56;  // octet base lane
    int s = offs[w];
    int cnt = deg[w];
    float dinv = rsqrtf((float)cnt + 1.0f);
    float2 a0 = make_float2(0.f, 0.f), a1 = a0, a2 = a0, a3 = a0;
    {  // self-loop
        uint4 v = hs4[(size_t)w * 8 + k];
        ACCV(v);
    }
    int rv = (k < cnt) ? csr[s + k] : 0;  // lane k holds index of edge e+k
    int e = 0;
    while (e + 8 <= cnt) {
        int nx = e + 8 + k;
        int rvn = (nx < cnt) ? csr[s + nx] : 0;  // prefetch next 8 indices
#pragma unroll
        for (int j = 0; j < 8; ++j) {
            int r = __shfl(rv, lane8 + j);
            uint4 v = hs4[(size_t)r * 8 + k];
            ACCV(v);
        }
        rv = rvn;
        e += 8;
    }
    int m = cnt - e;
    for (int j = 0; j < m; ++j) {
        int r = __shfl(rv, lane8 + j);
        uint4 v = hs4[(size_t)r * 8 + k];
        ACCV(v);
    }
    float4 bA = ((const float4*)b1)[2 * k];
    float4 bB = ((const float4*)b1)[2 * k + 1];
    float4 wA = ((const float4*)W2)[2 * k];
    float4 wB = ((const float4*)W2)[2 * k + 1];
    float p = fmaxf(fmaf(dinv, a0.x, bA.x), 0.f) * wA.x
            + fmaxf(fmaf(dinv, a0.y, bA.y), 0.f) * wA.y
            + fmaxf(fmaf(dinv, a1.x, bA.z), 0.f) * wA.z
            + fmaxf(fmaf(dinv, a1.y, bA.w), 0.f) * wA.w
            + fmaxf(fmaf(dinv, a2.x, bB.x), 0.f) * wB.x
            + fmaxf(fmaf(dinv, a2.y, bB.y), 0.f) * wB.y
            + fmaxf(fmaf(dinv, a3.x, bB.z), 0.f) * wB.z
            + fmaxf(fmaf(dinv, a3.y, bB.w), 0.f) * wB.w;
    p += __shfl_xor(p, 1);
    p += __shfl_xor(p, 2);
    p += __shfl_xor(p, 4);
    if ((lane & 7) == 0) hs2[w] = dinv * p;
}

__global__ __launch_bounds__(256) void pull2_kernel(
    const float* __restrict__ hs2, const int* __restrict__ offs,
    const int* __restrict__ deg, const int* __restrict__ csr,
    const float* __restrict__ b2, float* __restrict__ out, int N) {
    int i = blockIdx.x * blockDim.x + threadIdx.x;
    if (i >= N) return;
    int s = offs[i];
    int cnt = deg[i];
    float dinv = rsqrtf((float)cnt + 1.0f);
    float a0 = hs2[i];  // self-loop
    float a1 = 0.f, a2 = 0.f, a3 = 0.f;
    float a4 = 0.f, a5 = 0.f, a6 = 0.f, a7 = 0.f;
    int kk = 0;
    for (; kk + 8 <= cnt; kk += 8) {
        a0 += hs2[csr[s + kk]];
        a1 += hs2[csr[s + kk + 1]];
        a2 += hs2[csr[s + kk + 2]];
        a3 += hs2[csr[s + kk + 3]];
        a4 += hs2[csr[s + kk + 4]];
        a5 += hs2[csr[s + kk + 5]];
        a6 += hs2[csr[s + kk + 6]];
        a7 += hs2[csr[s + kk + 7]];
    }
    for (; kk < cnt; ++kk) a0 += hs2[csr[s + kk]];
    out[i] = fmaf(dinv, ((a0 + a1) + (a2 + a3)) + ((a4 + a5) + (a6 + a7)), b2[0]);
}

extern "C" void kernel_launch(void* const* d_in, const int* in_sizes, int n_in,
                              void* d_out, int out_size, void* d_ws, size_t ws_size,
                              hipStream_t stream) {
    const float* x = (const float*)d_in[0];
    const void* ei = d_in[1];
    const float* W1 = (const float*)d_in[2];
    const float* b1 = (const float*)d_in[3];
    const float* W2 = (const float*)d_in[4];
    const float* b2 = (const float*)d_in[5];
    float* out = (float*)d_out;

    int N = in_sizes[0] / 128;
    int E = in_sizes[1] / 2;
    int NB = (N + (1 << SHIFT) - 1) >> SHIFT;        // buckets (<= MAXB)
    int cap = ((2 * (E / NB)) / 256 + 2) * 256;      // 2x mean: safe for random input
    int nAblk = 512;
    int nGblk = (N + 63) / 64;

    char* p = (char*)d_ws;
    unsigned* hs_u = (unsigned*)p;  p += (size_t)N * 32 * sizeof(unsigned);
    float* hs2 = (float*)p;         p += (size_t)N * sizeof(float);
    int* offs = (int*)p;            p += (size_t)N * sizeof(int);
    int* deg = (int*)p;             p += (size_t)N * sizeof(int);
    unsigned* pairs = (unsigned*)p; p += (size_t)NB * cap * sizeof(unsigned);
    int* csr = (int*)p;             p += (size_t)NB * cap * sizeof(int);
    int* gcursor = (int*)p;         p += MAXB * sizeof(int);

    (void)hipMemsetAsync(gcursor, 0, MAXB * sizeof(int), stream);
    fusedA_kernel<<<nAblk + nGblk, 256, 0, stream>>>(ei, gcursor, pairs, E, cap, NB, x,
                                                     W1, hs_u, N, nAblk);
    binB_kernel<<<NB, 256, 0, stream>>>(pairs, gcursor, csr, offs, deg, hs_u, N, cap);
    pull1_kernel<<<((size_t)N * 8 + 255) / 256, 256, 0, stream>>>(
        (const uint4*)hs_u, offs, deg, csr, b1, W2, hs2, N);
    pull2_kernel<<<(N + 255) / 256, 256, 0, stream>>>(hs2, offs, deg, csr, b2, out, N);
}